// Round 1
// baseline (992.011 us; speedup 1.0000x reference)
//
#include <hip/hip_runtime.h>

#define NN    20000
#define NE    160000
#define NETOT 180000
#define NB    128

typedef __attribute__((ext_vector_type(4))) float f32x4;
typedef __attribute__((ext_vector_type(8))) short s16x8;

__device__ __forceinline__ unsigned short f2bf(float f){
  unsigned u = __float_as_uint(f);
  return (unsigned short)((u + 0x7FFFu + ((u >> 16) & 1u)) >> 16);
}
__device__ __forceinline__ float bf2f(unsigned short h){
  return __uint_as_float(((unsigned)h) << 16);
}
__device__ __forceinline__ unsigned fenc(float f){
  unsigned u = __float_as_uint(f);
  return (u & 0x80000000u) ? ~u : (u | 0x80000000u);
}
__device__ __forceinline__ float fdec(unsigned v){
  return __uint_as_float((v & 0x80000000u) ? (v ^ 0x80000000u) : ~v);
}
__device__ __forceinline__ void gload16(const void* g, void* l){
  __builtin_amdgcn_global_load_lds((const __attribute__((address_space(1))) void*)g,
                                   (__attribute__((address_space(3))) void*)l, 16, 0, 0);
}

// ---------- split f32 -> bf16 hi/lo (elementwise, float4-vectorized) ----------
__global__ void k_split(const float* __restrict__ in, unsigned short* __restrict__ hi,
                        unsigned short* __restrict__ lo, int n4){
  int i = blockIdx.x * blockDim.x + threadIdx.x;
  if (i >= n4) return;
  float4 v = ((const float4*)in)[i];
  ushort4 h, l;
  h.x = f2bf(v.x); l.x = f2bf(v.x - bf2f(h.x));
  h.y = f2bf(v.y); l.y = f2bf(v.y - bf2f(h.y));
  h.z = f2bf(v.z); l.z = f2bf(v.z - bf2f(h.z));
  h.w = f2bf(v.w); l.w = f2bf(v.w - bf2f(h.w));
  ((ushort4*)hi)[i] = h;
  ((ushort4*)lo)[i] = l;
}

// ---------- transpose + split: W[K][N] -> WT_hi/lo[N][K] ----------
__global__ void k_tsplit(const float* __restrict__ W, unsigned short* __restrict__ Thi,
                         unsigned short* __restrict__ Tlo, int K, int N){
  __shared__ float tile[32][33];
  int tx = threadIdx.x, ty = threadIdx.y;
  int n = blockIdx.x * 32 + tx, k = blockIdx.y * 32 + ty;
  tile[ty][tx] = W[(size_t)k * N + n];
  __syncthreads();
  int n2 = blockIdx.x * 32 + ty, k2 = blockIdx.y * 32 + tx;
  float f = tile[tx][ty];
  unsigned short h = f2bf(f);
  Thi[(size_t)n2 * K + k2] = h;
  Tlo[(size_t)n2 * K + k2] = f2bf(f - bf2f(h));
}

// ---------- split-precision bf16 MFMA GEMM: C[M,N] = A[M,K] @ BT[N,K]^T ----------
// A given as (Ahi,Alo), B^T as (BThi,BTlo). acc += Ah*Bh + Ah*Bl + Al*Bh.
__global__ __launch_bounds__(256)
void gemm_split(const unsigned short* __restrict__ Ahi, const unsigned short* __restrict__ Alo,
                const unsigned short* __restrict__ BThi, const unsigned short* __restrict__ BTlo,
                float* __restrict__ C, int M, int N, int K){
  __shared__ unsigned short lds[4][128 * 32];   // Ahi, Alo, Bhi, Blo tiles (32 KB)
  const int t = threadIdx.x;
  const int lane = t & 63;
  const int w = t >> 6;
  const int wr = w >> 1, wc = w & 1;
  const int ntile = N >> 7;
  const int mt = blockIdx.x / ntile;
  const int nt = blockIdx.x % ntile;
  const int m0 = mt << 7, n0 = nt << 7;

  f32x4 acc[4][4];
#pragma unroll
  for (int i = 0; i < 4; ++i)
#pragma unroll
    for (int j = 0; j < 4; ++j) acc[i][j] = (f32x4){0.f, 0.f, 0.f, 0.f};

  const int srow = t >> 2;          // 0..63 (row within 64-row half)
  const int scol = (t & 3) << 3;    // 0,8,16,24 (bf16 col)
  const int loff = t << 3;          // element offset in LDS half (t*8)

  for (int k0 = 0; k0 < K; k0 += 32){
    __syncthreads();                // previous iteration's LDS reads done
#pragma unroll
    for (int half = 0; half < 2; ++half){
      int ar = m0 + half * 64 + srow; if (ar >= M) ar = M - 1;   // clamp M-tail
      size_t ao = (size_t)ar * K + (k0 + scol);
      int brr = n0 + half * 64 + srow;
      size_t bo = (size_t)brr * K + (k0 + scol);
      int lo_ = half * 2048 + loff;
      gload16(Ahi + ao,  &lds[0][lo_]);
      gload16(Alo + ao,  &lds[1][lo_]);
      gload16(BThi + bo, &lds[2][lo_]);
      gload16(BTlo + bo, &lds[3][lo_]);
    }
    __syncthreads();                // staging visible (compiler drains vmcnt)

    s16x8 ah[4], al[4], bh[4], bl[4];
    const int rka = (lane >> 4) << 3;
#pragma unroll
    for (int mi = 0; mi < 4; ++mi){
      int row = wr * 64 + mi * 16 + (lane & 15);
      ah[mi] = *(const s16x8*)&lds[0][row * 32 + rka];
      al[mi] = *(const s16x8*)&lds[1][row * 32 + rka];
    }
#pragma unroll
    for (int ni = 0; ni < 4; ++ni){
      int row = wc * 64 + ni * 16 + (lane & 15);
      bh[ni] = *(const s16x8*)&lds[2][row * 32 + rka];
      bl[ni] = *(const s16x8*)&lds[3][row * 32 + rka];
    }
#pragma unroll
    for (int mi = 0; mi < 4; ++mi)
#pragma unroll
      for (int ni = 0; ni < 4; ++ni){
        acc[mi][ni] = __builtin_amdgcn_mfma_f32_16x16x32_bf16(ah[mi], bh[ni], acc[mi][ni], 0, 0, 0);
        acc[mi][ni] = __builtin_amdgcn_mfma_f32_16x16x32_bf16(ah[mi], bl[ni], acc[mi][ni], 0, 0, 0);
        acc[mi][ni] = __builtin_amdgcn_mfma_f32_16x16x32_bf16(al[mi], bh[ni], acc[mi][ni], 0, 0, 0);
      }
  }
  // epilogue: C/D layout col=lane&15, row=(lane>>4)*4+r  [m89/m91-verified]
#pragma unroll
  for (int mi = 0; mi < 4; ++mi)
#pragma unroll
    for (int ni = 0; ni < 4; ++ni){
      int col = n0 + wc * 64 + ni * 16 + (lane & 15);
#pragma unroll
      for (int r = 0; r < 4; ++r){
        int row = m0 + wr * 64 + mi * 16 + ((lane >> 4) << 2) + r;
        if (row < M) C[(size_t)row * N + col] = acc[mi][ni][r];
      }
    }
}

// ---------- per-node alpha_src/alpha_dst: sum_c xw[n,h,c]*a[h,c] ----------
template<int C>
__global__ void k_alpha(const float* __restrict__ xw, const float* __restrict__ a_src,
                        const float* __restrict__ a_dst, float* __restrict__ asrc,
                        float* __restrict__ adst){
  const int n = blockIdx.x, t = threadIdx.x;
  constexpr int ITER = C / 256;
  const float4* xw4 = (const float4*)(xw + (size_t)n * 4 * C);
  const float4* s4 = (const float4*)a_src;
  const float4* d4 = (const float4*)a_dst;
  __shared__ float psrc[8], pdst[8];
  __shared__ int phead[8];
#pragma unroll
  for (int i = 0; i < ITER; ++i){
    int j = i * 256 + t;                       // float4 index, head = j/(C/4)
    float4 v = xw4[j], s = s4[j], d = d4[j];
    float ps = v.x * s.x + v.y * s.y + v.z * s.z + v.w * s.w;
    float pd = v.x * d.x + v.y * d.y + v.z * d.z + v.w * d.w;
#pragma unroll
    for (int off = 32; off; off >>= 1){
      ps += __shfl_xor(ps, off);
      pd += __shfl_xor(pd, off);
    }
    if ((t & 63) == 0){
      int slot = i * 4 + (t >> 6);
      psrc[slot] = ps; pdst[slot] = pd; phead[slot] = j / (C / 4);
    }
  }
  __syncthreads();
  if (t < 4){
    float ss = 0.f, sd = 0.f;
    for (int s2 = 0; s2 < ITER * 4; ++s2)
      if (phead[s2] == t){ ss += psrc[s2]; sd += pdst[s2]; }
    asrc[n * 4 + t] = ss;
    adst[n * 4 + t] = sd;
  }
}

// ---------- CSR build ----------
__global__ void k_count(const int* __restrict__ ei, int* __restrict__ counts){
  int e = blockIdx.x * blockDim.x + threadIdx.x;
  if (e >= NETOT) return;
  int d = (e < NE) ? ei[NE + e] : (e - NE);
  atomicAdd(&counts[d], 1);
}
__global__ void k_scan(const int* __restrict__ counts, int* __restrict__ row_ptr,
                       int* __restrict__ cursor){
  __shared__ int lds[1024];
  int t = threadIdx.x;
  int base = 0;
  for (int c0 = 0; c0 < NN; c0 += 1024){
    int i = c0 + t;
    int v = (i < NN) ? counts[i] : 0;
    __syncthreads();
    lds[t] = v;
    __syncthreads();
    for (int off = 1; off < 1024; off <<= 1){
      int x = (t >= off) ? lds[t - off] : 0;
      __syncthreads();
      lds[t] += x;
      __syncthreads();
    }
    int excl = base + lds[t] - v;
    if (i < NN){ row_ptr[i] = excl; cursor[i] = excl; }
    base += lds[1023];
  }
  if (t == 0) row_ptr[NN] = base;
}
__global__ void k_scatter(const int* __restrict__ ei, int* __restrict__ cursor,
                          int* __restrict__ csr_src, int* __restrict__ csr_eid){
  int e = blockIdx.x * blockDim.x + threadIdx.x;
  if (e >= NETOT) return;
  int s, d;
  if (e < NE){ s = ei[e]; d = ei[NE + e]; } else { s = d = e - NE; }
  int pos = atomicAdd(&cursor[d], 1);
  csr_src[pos] = s;
  csr_eid[pos] = e;
}

// ---------- edge softmax passes ----------
__global__ void k_emax(const int* __restrict__ ei, const float* __restrict__ asrc,
                       const float* __restrict__ adst, unsigned* __restrict__ menc){
  int e = blockIdx.x * blockDim.x + threadIdx.x;
  if (e >= NETOT) return;
  int s, d;
  if (e < NE){ s = ei[e]; d = ei[NE + e]; } else { s = d = e - NE; }
  float4 a = ((const float4*)asrc)[s];
  float4 b = ((const float4*)adst)[d];
  float v[4] = {a.x + b.x, a.y + b.y, a.z + b.z, a.w + b.w};
#pragma unroll
  for (int h = 0; h < 4; ++h){
    float x = v[h] > 0.f ? v[h] : 0.2f * v[h];
    atomicMax(&menc[d * 4 + h], fenc(x));
  }
}
__global__ void k_eexp(const int* __restrict__ ei, const float* __restrict__ asrc,
                       const float* __restrict__ adst, const unsigned* __restrict__ menc,
                       float* __restrict__ ex, float* __restrict__ den){
  int e = blockIdx.x * blockDim.x + threadIdx.x;
  if (e >= NETOT) return;
  int s, d;
  if (e < NE){ s = ei[e]; d = ei[NE + e]; } else { s = d = e - NE; }
  float4 a = ((const float4*)asrc)[s];
  float4 b = ((const float4*)adst)[d];
  float v[4] = {a.x + b.x, a.y + b.y, a.z + b.z, a.w + b.w};
#pragma unroll
  for (int h = 0; h < 4; ++h){
    float x = v[h] > 0.f ? v[h] : 0.2f * v[h];
    float m = fdec(menc[d * 4 + h]);
    float xv = expf(x - m);
    ex[e * 4 + h] = xv;
    atomicAdd(&den[d * 4 + h], xv);
  }
}

// ---------- aggregation: out[n,c] = mean_h sum_{e: dst=n} alpha[e,h]*xw[src,h,c] + b[c] ----------
template<int C>                       // blockDim = C/2, one block per node
__global__ void k_agg(const float* __restrict__ xw, const int* __restrict__ row_ptr,
                      const int* __restrict__ csr_src, const int* __restrict__ csr_eid,
                      const float* __restrict__ ex, const float* __restrict__ den,
                      const float* __restrict__ bias, float* __restrict__ out){
  const int n = blockIdx.x, t = threadIdx.x;
  float4 dv = ((const float4*)den)[n];
  float rd[4] = {1.f / (dv.x + 1e-16f), 1.f / (dv.y + 1e-16f),
                 1.f / (dv.z + 1e-16f), 1.f / (dv.w + 1e-16f)};
  float acc[4][2] = {};
  int beg = row_ptr[n], end = row_ptr[n + 1];
  const float2* xw2 = (const float2*)xw;
  for (int i = beg; i < end; ++i){
    int s = csr_src[i];
    int e = csr_eid[i];
    float4 exv = ((const float4*)ex)[e];
    float al[4] = {exv.x * rd[0], exv.y * rd[1], exv.z * rd[2], exv.w * rd[3]};
    size_t sb = (size_t)s * (2 * C);
#pragma unroll
    for (int h = 0; h < 4; ++h){
      float2 v = xw2[sb + h * (C / 2) + t];
      acc[h][0] += al[h] * v.x;
      acc[h][1] += al[h] * v.y;
    }
  }
  float o0 = 0.25f * (acc[0][0] + acc[1][0] + acc[2][0] + acc[3][0]) + bias[2 * t];
  float o1 = 0.25f * (acc[0][1] + acc[1][1] + acc[2][1] + acc[3][1]) + bias[2 * t + 1];
  ((float2*)out)[(size_t)n * (C / 2) + t] = make_float2(o0, o1);
}

// ---------- pooling (batch sorted -> run-length partials) ----------
__global__ void k_pool(const float* __restrict__ h2, const int* __restrict__ batch,
                       float* __restrict__ sums, int* __restrict__ cnt){
  int n0 = blockIdx.x * 64;
  int t = threadIdx.x;
  int nend = n0 + 64; if (nend > NN) nend = NN;
  int cur = batch[n0];
  float acc = 0.f; int run = 0;
  for (int n = n0; n < nend; ++n){
    int b = batch[n];
    if (b != cur){
      atomicAdd(&sums[cur * 256 + t], acc);
      if (t == 0) atomicAdd(&cnt[cur], run);
      acc = 0.f; run = 0; cur = b;
    }
    acc += h2[(size_t)n * 256 + t];
    run++;
  }
  atomicAdd(&sums[cur * 256 + t], acc);
  if (t == 0) atomicAdd(&cnt[cur], run);
}

__global__ void k_fc(const float* __restrict__ sums, const int* __restrict__ cnt,
                     const float* __restrict__ fcW, const float* __restrict__ fcb,
                     float* __restrict__ out){
  int b = blockIdx.x, t = threadIdx.x;
  int c = cnt[b]; if (c < 1) c = 1;
  float inv = 1.f / (float)c;
  float v = sums[b * 256 + t] * inv;
  float p0 = v * fcW[t * 2];
  float p1 = v * fcW[t * 2 + 1];
#pragma unroll
  for (int off = 32; off; off >>= 1){
    p0 += __shfl_xor(p0, off);
    p1 += __shfl_xor(p1, off);
  }
  __shared__ float r0[4], r1[4];
  if ((t & 63) == 0){ r0[t >> 6] = p0; r1[t >> 6] = p1; }
  __syncthreads();
  if (t == 0){
    out[b * 2 + 0] = r0[0] + r0[1] + r0[2] + r0[3] + fcb[0];
    out[b * 2 + 1] = r1[0] + r1[1] + r1[2] + r1[3] + fcb[1];
  }
}

extern "C" void kernel_launch(void* const* d_in, const int* in_sizes, int n_in,
                              void* d_out, int out_size, void* d_ws, size_t ws_size,
                              hipStream_t stream){
  const float* x      = (const float*)d_in[0];
  const int*   ei     = (const int*)d_in[1];
  const int*   batch  = (const int*)d_in[2];
  const float* W1     = (const float*)d_in[3];
  const float* a_src1 = (const float*)d_in[4];
  const float* a_dst1 = (const float*)d_in[5];
  const float* b1     = (const float*)d_in[6];
  const float* W2     = (const float*)d_in[7];
  const float* a_src2 = (const float*)d_in[8];
  const float* a_dst2 = (const float*)d_in[9];
  const float* b2     = (const float*)d_in[10];
  const float* fcW    = (const float*)d_in[11];
  const float* fcb    = (const float*)d_in[12];
  float* out = (float*)d_out;
  (void)in_sizes; (void)n_in; (void)out_size; (void)ws_size;

  char* ws = (char*)d_ws;
  size_t off = 0;
  auto take = [&](size_t bytes) -> char* {
    char* p = ws + off;
    off += (bytes + 255) & ~(size_t)255;
    return p;
  };
  // slab0: xw1 [20000,2048] f32 (164 MB); later aliased by xw2 / h1_hi / h1_lo / h2
  char* slab0 = take(163840000);
  float* xw1 = (float*)slab0;
  float* xw2 = (float*)slab0;                                    // 82 MB
  unsigned short* h1_hi = (unsigned short*)(slab0 + 81920000);   // 20.5 MB
  unsigned short* h1_lo = (unsigned short*)(slab0 + 102400000);  // 20.5 MB
  float* h2 = (float*)(slab0 + 122880000);                       // 20.5 MB
  // slab1: x_hi/x_lo (61.5 MB); later aliased by h1 (41 MB)
  char* slab1 = take(61440000);
  unsigned short* x_hi = (unsigned short*)slab1;
  unsigned short* x_lo = (unsigned short*)(slab1 + 30720000);
  float* h1 = (float*)slab1;
  // persistent small buffers
  unsigned short* W1T_hi = (unsigned short*)take(3145728);
  unsigned short* W1T_lo = (unsigned short*)take(3145728);
  unsigned short* W2T_hi = (unsigned short*)take(1048576);
  unsigned short* W2T_lo = (unsigned short*)take(1048576);
  float* asrc   = (float*)take(320000);
  float* adst   = (float*)take(320000);
  unsigned* menc = (unsigned*)take(320000);
  float* den    = (float*)take(320000);
  float* ex     = (float*)take((size_t)NETOT * 16);
  int* counts   = (int*)take(80004);
  int* row_ptr  = (int*)take(80004);
  int* cursor   = (int*)take(80004);
  int* csr_src  = (int*)take(720000);
  int* csr_eid  = (int*)take(720000);
  float* sums   = (float*)take(131072);
  int* cnt      = (int*)take(512);

  const int egrid = (NETOT + 255) / 256;

  // ---- CSR (shared by both layers) ----
  hipMemsetAsync(counts, 0, NN * 4, stream);
  k_count<<<egrid, 256, 0, stream>>>(ei, counts);
  k_scan<<<1, 1024, 0, stream>>>(counts, row_ptr, cursor);
  k_scatter<<<egrid, 256, 0, stream>>>(ei, cursor, csr_src, csr_eid);

  // ---- layer 1 ----
  k_split<<<(3840000 + 255) / 256, 256, 0, stream>>>(x, x_hi, x_lo, 3840000);
  k_tsplit<<<dim3(2048 / 32, 768 / 32), dim3(32, 32), 0, stream>>>(W1, W1T_hi, W1T_lo, 768, 2048);
  gemm_split<<<157 * 16, 256, 0, stream>>>(x_hi, x_lo, W1T_hi, W1T_lo, xw1, NN, 2048, 768);
  k_alpha<512><<<NN, 256, 0, stream>>>(xw1, a_src1, a_dst1, asrc, adst);
  hipMemsetAsync(menc, 0, 320000, stream);
  hipMemsetAsync(den, 0, 320000, stream);
  k_emax<<<egrid, 256, 0, stream>>>(ei, asrc, adst, menc);
  k_eexp<<<egrid, 256, 0, stream>>>(ei, asrc, adst, menc, ex, den);
  k_agg<512><<<NN, 256, 0, stream>>>(xw1, row_ptr, csr_src, csr_eid, ex, den, b1, h1);

  // ---- layer 2 ----
  k_split<<<(2560000 + 255) / 256, 256, 0, stream>>>(h1, h1_hi, h1_lo, 2560000);
  k_tsplit<<<dim3(1024 / 32, 512 / 32), dim3(32, 32), 0, stream>>>(W2, W2T_hi, W2T_lo, 512, 1024);
  gemm_split<<<157 * 8, 256, 0, stream>>>(h1_hi, h1_lo, W2T_hi, W2T_lo, xw2, NN, 1024, 512);
  k_alpha<256><<<NN, 256, 0, stream>>>(xw2, a_src2, a_dst2, asrc, adst);
  hipMemsetAsync(menc, 0, 320000, stream);
  hipMemsetAsync(den, 0, 320000, stream);
  k_emax<<<egrid, 256, 0, stream>>>(ei, asrc, adst, menc);
  k_eexp<<<egrid, 256, 0, stream>>>(ei, asrc, adst, menc, ex, den);
  k_agg<256><<<NN, 128, 0, stream>>>(xw2, row_ptr, csr_src, csr_eid, ex, den, b2, h2);

  // ---- pool + fc ----
  hipMemsetAsync(sums, 0, 131072, stream);
  hipMemsetAsync(cnt, 0, 512, stream);
  k_pool<<<(NN + 63) / 64, 256, 0, stream>>>(h2, batch, sums, cnt);
  k_fc<<<NB, 256, 0, stream>>>(sums, cnt, fcW, fcb, out);
}

// Round 2
// 676.635 us; speedup vs baseline: 1.4661x; 1.4661x over previous
//
#include <hip/hip_runtime.h>

#define NN    20000
#define NE    160000
#define NETOT 180000
#define NB    128

typedef __attribute__((ext_vector_type(4))) float f32x4;
typedef __attribute__((ext_vector_type(8))) short s16x8;

__device__ __forceinline__ unsigned short f2bf(float f){
  unsigned u = __float_as_uint(f);
  return (unsigned short)((u + 0x7FFFu + ((u >> 16) & 1u)) >> 16);
}
__device__ __forceinline__ float bf2f(unsigned short h){
  return __uint_as_float(((unsigned)h) << 16);
}
__device__ __forceinline__ unsigned fenc(float f){
  unsigned u = __float_as_uint(f);
  return (u & 0x80000000u) ? ~u : (u | 0x80000000u);
}
__device__ __forceinline__ float fdec(unsigned v){
  return __uint_as_float((v & 0x80000000u) ? (v ^ 0x80000000u) : ~v);
}
__device__ __forceinline__ void gload16(const void* g, void* l){
  __builtin_amdgcn_global_load_lds((const __attribute__((address_space(1))) void*)g,
                                   (__attribute__((address_space(3))) void*)l, 16, 0, 0);
}

// ---------- f32 -> bf16 convert (float4-vectorized) ----------
__global__ void k_cvt(const float* __restrict__ in, unsigned short* __restrict__ outp, int n4){
  int i = blockIdx.x * blockDim.x + threadIdx.x;
  if (i >= n4) return;
  float4 v = ((const float4*)in)[i];
  ushort4 h;
  h.x = f2bf(v.x); h.y = f2bf(v.y); h.z = f2bf(v.z); h.w = f2bf(v.w);
  ((ushort4*)outp)[i] = h;
}

// ---------- transpose + convert: W[K][N] -> WT[N][K] bf16 ----------
__global__ void k_tcvt(const float* __restrict__ W, unsigned short* __restrict__ T, int K, int N){
  __shared__ float tile[32][33];
  int tx = threadIdx.x, ty = threadIdx.y;
  int n = blockIdx.x * 32 + tx, k = blockIdx.y * 32 + ty;
  tile[ty][tx] = W[(size_t)k * N + n];
  __syncthreads();
  int n2 = blockIdx.x * 32 + ty, k2 = blockIdx.y * 32 + tx;
  T[(size_t)n2 * K + k2] = f2bf(tile[tx][ty]);
}

// ---------- bf16 MFMA GEMM: C[M,N] = A[M,K] @ BT[N,K]^T, bf16 out ----------
__global__ __launch_bounds__(256)
void gemm_bf16(const unsigned short* __restrict__ A, const unsigned short* __restrict__ BT,
               unsigned short* __restrict__ C, int M, int N, int K){
  __shared__ unsigned short lds[2][128 * 32];   // A-tile, B-tile (16 KB)
  const int t = threadIdx.x;
  const int lane = t & 63;
  const int w = t >> 6;
  const int wr = w >> 1, wc = w & 1;
  const int ntile = N >> 7;
  const int mt = blockIdx.x / ntile;
  const int nt = blockIdx.x % ntile;
  const int m0 = mt << 7, n0 = nt << 7;

  f32x4 acc[4][4];
#pragma unroll
  for (int i = 0; i < 4; ++i)
#pragma unroll
    for (int j = 0; j < 4; ++j) acc[i][j] = (f32x4){0.f, 0.f, 0.f, 0.f};

  const int srow = t >> 2;          // 0..63
  const int scol = (t & 3) << 3;    // 0,8,16,24
  const int loff = t << 3;

  for (int k0 = 0; k0 < K; k0 += 32){
    __syncthreads();
#pragma unroll
    for (int half = 0; half < 2; ++half){
      int ar = m0 + half * 64 + srow; if (ar >= M) ar = M - 1;
      int br = n0 + half * 64 + srow;
      int lo_ = half * 2048 + loff;
      gload16(A + (size_t)ar * K + (k0 + scol),  &lds[0][lo_]);
      gload16(BT + (size_t)br * K + (k0 + scol), &lds[1][lo_]);
    }
    __syncthreads();

    s16x8 ah[4], bh[4];
    const int rka = (lane >> 4) << 3;
#pragma unroll
    for (int mi = 0; mi < 4; ++mi){
      int row = wr * 64 + mi * 16 + (lane & 15);
      ah[mi] = *(const s16x8*)&lds[0][row * 32 + rka];
    }
#pragma unroll
    for (int ni = 0; ni < 4; ++ni){
      int row = wc * 64 + ni * 16 + (lane & 15);
      bh[ni] = *(const s16x8*)&lds[1][row * 32 + rka];
    }
#pragma unroll
    for (int mi = 0; mi < 4; ++mi)
#pragma unroll
      for (int ni = 0; ni < 4; ++ni)
        acc[mi][ni] = __builtin_amdgcn_mfma_f32_16x16x32_bf16(ah[mi], bh[ni], acc[mi][ni], 0, 0, 0);
  }
  // C/D layout: col=lane&15, row=(lane>>4)*4+r  [m89/m91-verified]
#pragma unroll
  for (int mi = 0; mi < 4; ++mi)
#pragma unroll
    for (int ni = 0; ni < 4; ++ni){
      int col = n0 + wc * 64 + ni * 16 + (lane & 15);
#pragma unroll
      for (int r = 0; r < 4; ++r){
        int row = m0 + wr * 64 + mi * 16 + ((lane >> 4) << 2) + r;
        if (row < M) C[(size_t)row * N + col] = f2bf(acc[mi][ni][r]);
      }
    }
}

// ---------- per-node alpha_src/alpha_dst from bf16 xw ----------
template<int C>                       // block = C/2 threads
__global__ void k_alpha(const unsigned short* __restrict__ xw, const float* __restrict__ a_src,
                        const float* __restrict__ a_dst, float* __restrict__ asrc,
                        float* __restrict__ adst){
  const int n = blockIdx.x, t = threadIdx.x;
  constexpr int W = C / 8;            // lanes per head group (64 or 32)
  const int head = (t * 8) / C;
  const int c0 = (t * 8) % C;
  s16x8 v = *(const s16x8*)(xw + (size_t)n * 4 * C + t * 8);
  float4 s0 = *(const float4*)(a_src + head * C + c0);
  float4 s1 = *(const float4*)(a_src + head * C + c0 + 4);
  float4 d0 = *(const float4*)(a_dst + head * C + c0);
  float4 d1 = *(const float4*)(a_dst + head * C + c0 + 4);
  float f[8];
#pragma unroll
  for (int j = 0; j < 8; ++j) f[j] = bf2f((unsigned short)v[j]);
  float ps = f[0]*s0.x + f[1]*s0.y + f[2]*s0.z + f[3]*s0.w
           + f[4]*s1.x + f[5]*s1.y + f[6]*s1.z + f[7]*s1.w;
  float pd = f[0]*d0.x + f[1]*d0.y + f[2]*d0.z + f[3]*d0.w
           + f[4]*d1.x + f[5]*d1.y + f[6]*d1.z + f[7]*d1.w;
#pragma unroll
  for (int off = W / 2; off; off >>= 1){
    ps += __shfl_xor(ps, off);
    pd += __shfl_xor(pd, off);
  }
  if ((t & (W - 1)) == 0){
    asrc[n * 4 + head] = ps;
    adst[n * 4 + head] = pd;
  }
}

// ---------- CSR build ----------
__global__ void k_count(const int* __restrict__ ei, int* __restrict__ counts){
  int e = blockIdx.x * blockDim.x + threadIdx.x;
  if (e >= NETOT) return;
  int d = (e < NE) ? ei[NE + e] : (e - NE);
  atomicAdd(&counts[d], 1);
}
__global__ void k_scan(const int* __restrict__ counts, int* __restrict__ row_ptr,
                       int* __restrict__ cursor){
  __shared__ int lds[1024];
  int t = threadIdx.x;
  int base = 0;
  for (int c0 = 0; c0 < NN; c0 += 1024){
    int i = c0 + t;
    int v = (i < NN) ? counts[i] : 0;
    __syncthreads();
    lds[t] = v;
    __syncthreads();
    for (int off = 1; off < 1024; off <<= 1){
      int x = (t >= off) ? lds[t - off] : 0;
      __syncthreads();
      lds[t] += x;
      __syncthreads();
    }
    int excl = base + lds[t] - v;
    if (i < NN){ row_ptr[i] = excl; cursor[i] = excl; }
    base += lds[1023];
  }
  if (t == 0) row_ptr[NN] = base;
}
__global__ void k_scatter(const int* __restrict__ ei, int* __restrict__ cursor,
                          int* __restrict__ csr_src, int* __restrict__ csr_eid){
  int e = blockIdx.x * blockDim.x + threadIdx.x;
  if (e >= NETOT) return;
  int s, d;
  if (e < NE){ s = ei[e]; d = ei[NE + e]; } else { s = d = e - NE; }
  int pos = atomicAdd(&cursor[d], 1);
  csr_src[pos] = s;
  csr_eid[pos] = e;
}

// ---------- edge softmax passes ----------
__global__ void k_emax(const int* __restrict__ ei, const float* __restrict__ asrc,
                       const float* __restrict__ adst, unsigned* __restrict__ menc){
  int e = blockIdx.x * blockDim.x + threadIdx.x;
  if (e >= NETOT) return;
  int s, d;
  if (e < NE){ s = ei[e]; d = ei[NE + e]; } else { s = d = e - NE; }
  float4 a = ((const float4*)asrc)[s];
  float4 b = ((const float4*)adst)[d];
  float v[4] = {a.x + b.x, a.y + b.y, a.z + b.z, a.w + b.w};
#pragma unroll
  for (int h = 0; h < 4; ++h){
    float x = v[h] > 0.f ? v[h] : 0.2f * v[h];
    atomicMax(&menc[d * 4 + h], fenc(x));
  }
}
__global__ void k_eexp(const int* __restrict__ ei, const float* __restrict__ asrc,
                       const float* __restrict__ adst, const unsigned* __restrict__ menc,
                       float* __restrict__ ex, float* __restrict__ den){
  int e = blockIdx.x * blockDim.x + threadIdx.x;
  if (e >= NETOT) return;
  int s, d;
  if (e < NE){ s = ei[e]; d = ei[NE + e]; } else { s = d = e - NE; }
  float4 a = ((const float4*)asrc)[s];
  float4 b = ((const float4*)adst)[d];
  float v[4] = {a.x + b.x, a.y + b.y, a.z + b.z, a.w + b.w};
#pragma unroll
  for (int h = 0; h < 4; ++h){
    float x = v[h] > 0.f ? v[h] : 0.2f * v[h];
    float m = fdec(menc[d * 4 + h]);
    float xv = expf(x - m);
    ex[e * 4 + h] = xv;
    atomicAdd(&den[d * 4 + h], xv);
  }
}

// ---------- aggregation from bf16 xw ----------
template<int C, bool BF16OUT>         // block = C/2, one block per node
__global__ void k_agg(const unsigned short* __restrict__ xw, const int* __restrict__ row_ptr,
                      const int* __restrict__ csr_src, const int* __restrict__ csr_eid,
                      const float* __restrict__ ex, const float* __restrict__ den,
                      const float* __restrict__ bias, void* __restrict__ outp){
  const int n = blockIdx.x, t = threadIdx.x;
  float4 dv = ((const float4*)den)[n];
  float rd[4] = {1.f / (dv.x + 1e-16f), 1.f / (dv.y + 1e-16f),
                 1.f / (dv.z + 1e-16f), 1.f / (dv.w + 1e-16f)};
  float acc[4][2] = {};
  int beg = row_ptr[n], end = row_ptr[n + 1];
  for (int i = beg; i < end; ++i){
    int s = csr_src[i];
    int e = csr_eid[i];
    float4 exv = ((const float4*)ex)[e];
    float al[4] = {exv.x * rd[0], exv.y * rd[1], exv.z * rd[2], exv.w * rd[3]};
    const unsigned short* sb = xw + (size_t)s * 4 * C + 2 * t;
#pragma unroll
    for (int h = 0; h < 4; ++h){
      ushort2 v = *(const ushort2*)(sb + h * C);
      acc[h][0] += al[h] * bf2f(v.x);
      acc[h][1] += al[h] * bf2f(v.y);
    }
  }
  float o0 = 0.25f * (acc[0][0] + acc[1][0] + acc[2][0] + acc[3][0]) + bias[2 * t];
  float o1 = 0.25f * (acc[0][1] + acc[1][1] + acc[2][1] + acc[3][1]) + bias[2 * t + 1];
  if (BF16OUT){
    ushort2 o; o.x = f2bf(o0); o.y = f2bf(o1);
    ((ushort2*)outp)[(size_t)n * (C / 2) + t] = o;
  } else {
    ((float2*)outp)[(size_t)n * (C / 2) + t] = make_float2(o0, o1);
  }
}

// ---------- pooling (batch sorted -> run-length partials) ----------
__global__ void k_pool(const float* __restrict__ h2, const int* __restrict__ batch,
                       float* __restrict__ sums, int* __restrict__ cnt){
  int n0 = blockIdx.x * 64;
  int t = threadIdx.x;
  int nend = n0 + 64; if (nend > NN) nend = NN;
  int cur = batch[n0];
  float acc = 0.f; int run = 0;
  for (int n = n0; n < nend; ++n){
    int b = batch[n];
    if (b != cur){
      atomicAdd(&sums[cur * 256 + t], acc);
      if (t == 0) atomicAdd(&cnt[cur], run);
      acc = 0.f; run = 0; cur = b;
    }
    acc += h2[(size_t)n * 256 + t];
    run++;
  }
  atomicAdd(&sums[cur * 256 + t], acc);
  if (t == 0) atomicAdd(&cnt[cur], run);
}

__global__ void k_fc(const float* __restrict__ sums, const int* __restrict__ cnt,
                     const float* __restrict__ fcW, const float* __restrict__ fcb,
                     float* __restrict__ out){
  int b = blockIdx.x, t = threadIdx.x;
  int c = cnt[b]; if (c < 1) c = 1;
  float inv = 1.f / (float)c;
  float v = sums[b * 256 + t] * inv;
  float p0 = v * fcW[t * 2];
  float p1 = v * fcW[t * 2 + 1];
#pragma unroll
  for (int off = 32; off; off >>= 1){
    p0 += __shfl_xor(p0, off);
    p1 += __shfl_xor(p1, off);
  }
  __shared__ float r0[4], r1[4];
  if ((t & 63) == 0){ r0[t >> 6] = p0; r1[t >> 6] = p1; }
  __syncthreads();
  if (t == 0){
    out[b * 2 + 0] = r0[0] + r0[1] + r0[2] + r0[3] + fcb[0];
    out[b * 2 + 1] = r1[0] + r1[1] + r1[2] + r1[3] + fcb[1];
  }
}

extern "C" void kernel_launch(void* const* d_in, const int* in_sizes, int n_in,
                              void* d_out, int out_size, void* d_ws, size_t ws_size,
                              hipStream_t stream){
  const float* x      = (const float*)d_in[0];
  const int*   ei     = (const int*)d_in[1];
  const int*   batch  = (const int*)d_in[2];
  const float* W1     = (const float*)d_in[3];
  const float* a_src1 = (const float*)d_in[4];
  const float* a_dst1 = (const float*)d_in[5];
  const float* b1     = (const float*)d_in[6];
  const float* W2     = (const float*)d_in[7];
  const float* a_src2 = (const float*)d_in[8];
  const float* a_dst2 = (const float*)d_in[9];
  const float* b2     = (const float*)d_in[10];
  const float* fcW    = (const float*)d_in[11];
  const float* fcb    = (const float*)d_in[12];
  float* out = (float*)d_out;
  (void)in_sizes; (void)n_in; (void)out_size; (void)ws_size;

  char* ws = (char*)d_ws;
  size_t off = 0;
  auto take = [&](size_t bytes) -> char* {
    char* p = ws + off;
    off += (bytes + 255) & ~(size_t)255;
    return p;
  };
  // slab0: xw1 bf16 [20000,2048] (82 MB); later aliased by xw2 bf16 (41 MB)
  char* slab0 = take(81920000);
  unsigned short* xw1 = (unsigned short*)slab0;
  unsigned short* xw2 = (unsigned short*)slab0;
  unsigned short* x_bf  = (unsigned short*)take(30720000);  // [20000,768] bf16
  unsigned short* h1_bf = (unsigned short*)take(20480000);  // [20000,512] bf16
  float*          h2    = (float*)take(20480000);           // [20000,256] f32
  unsigned short* W1T = (unsigned short*)take(3145728);
  unsigned short* W2T = (unsigned short*)take(1048576);
  float* asrc   = (float*)take(320000);
  float* adst   = (float*)take(320000);
  unsigned* menc = (unsigned*)take(320000);
  float* den    = (float*)take(320000);
  float* ex     = (float*)take((size_t)NETOT * 16);
  int* counts   = (int*)take(80004);
  int* row_ptr  = (int*)take(80004);
  int* cursor   = (int*)take(80004);
  int* csr_src  = (int*)take(720000);
  int* csr_eid  = (int*)take(720000);
  float* sums   = (float*)take(131072);
  int* cnt      = (int*)take(512);

  const int egrid = (NETOT + 255) / 256;

  // ---- CSR (shared by both layers) ----
  hipMemsetAsync(counts, 0, NN * 4, stream);
  k_count<<<egrid, 256, 0, stream>>>(ei, counts);
  k_scan<<<1, 1024, 0, stream>>>(counts, row_ptr, cursor);
  k_scatter<<<egrid, 256, 0, stream>>>(ei, cursor, csr_src, csr_eid);

  // ---- layer 1 ----
  k_cvt<<<(3840000 + 255) / 256, 256, 0, stream>>>(x, x_bf, 3840000);
  k_tcvt<<<dim3(2048 / 32, 768 / 32), dim3(32, 32), 0, stream>>>(W1, W1T, 768, 2048);
  gemm_bf16<<<157 * 16, 256, 0, stream>>>(x_bf, W1T, xw1, NN, 2048, 768);
  k_alpha<512><<<NN, 256, 0, stream>>>(xw1, a_src1, a_dst1, asrc, adst);
  hipMemsetAsync(menc, 0, 320000, stream);
  hipMemsetAsync(den, 0, 320000, stream);
  k_emax<<<egrid, 256, 0, stream>>>(ei, asrc, adst, menc);
  k_eexp<<<egrid, 256, 0, stream>>>(ei, asrc, adst, menc, ex, den);
  k_agg<512, true><<<NN, 256, 0, stream>>>(xw1, row_ptr, csr_src, csr_eid, ex, den, b1, h1_bf);

  // ---- layer 2 ----
  k_tcvt<<<dim3(1024 / 32, 512 / 32), dim3(32, 32), 0, stream>>>(W2, W2T, 512, 1024);
  gemm_bf16<<<157 * 8, 256, 0, stream>>>(h1_bf, W2T, xw2, NN, 1024, 512);
  k_alpha<256><<<NN, 128, 0, stream>>>(xw2, a_src2, a_dst2, asrc, adst);
  hipMemsetAsync(menc, 0, 320000, stream);
  hipMemsetAsync(den, 0, 320000, stream);
  k_emax<<<egrid, 256, 0, stream>>>(ei, asrc, adst, menc);
  k_eexp<<<egrid, 256, 0, stream>>>(ei, asrc, adst, menc, ex, den);
  k_agg<256, false><<<NN, 128, 0, stream>>>(xw2, row_ptr, csr_src, csr_eid, ex, den, b2, h2);

  // ---- pool + fc ----
  hipMemsetAsync(sums, 0, 131072, stream);
  hipMemsetAsync(cnt, 0, 512, stream);
  k_pool<<<(NN + 63) / 64, 256, 0, stream>>>(h2, batch, sums, cnt);
  k_fc<<<NB, 256, 0, stream>>>(sums, cnt, fcW, fcb, out);
}

// Round 3
// 548.780 us; speedup vs baseline: 1.8077x; 1.2330x over previous
//
#include <hip/hip_runtime.h>

#define NN    20000
#define NE    160000
#define NETOT 180000
#define NB    128

typedef __attribute__((ext_vector_type(4))) float f32x4;
typedef __attribute__((ext_vector_type(8))) short s16x8;

__device__ __forceinline__ unsigned short f2bf(float f){
  unsigned u = __float_as_uint(f);
  return (unsigned short)((u + 0x7FFFu + ((u >> 16) & 1u)) >> 16);
}
__device__ __forceinline__ float bf2f(unsigned short h){
  return __uint_as_float(((unsigned)h) << 16);
}
__device__ __forceinline__ void gload16(const void* g, void* l){
  __builtin_amdgcn_global_load_lds((const __attribute__((address_space(1))) void*)g,
                                   (__attribute__((address_space(3))) void*)l, 16, 0, 0);
}

// ---------- f32 -> bf16 convert ----------
__global__ void k_cvt(const float* __restrict__ in, unsigned short* __restrict__ outp, int n4){
  int i = blockIdx.x * blockDim.x + threadIdx.x;
  if (i >= n4) return;
  float4 v = ((const float4*)in)[i];
  ushort4 h;
  h.x = f2bf(v.x); h.y = f2bf(v.y); h.z = f2bf(v.z); h.w = f2bf(v.w);
  ((ushort4*)outp)[i] = h;
}

// ---------- transpose + convert: W[K][N] -> WT[N][K] bf16 ----------
__global__ void k_tcvt(const float* __restrict__ W, unsigned short* __restrict__ T, int K, int N){
  __shared__ float tile[32][33];
  int tx = threadIdx.x, ty = threadIdx.y;
  int n = blockIdx.x * 32 + tx, k = blockIdx.y * 32 + ty;
  tile[ty][tx] = W[(size_t)k * N + n];
  __syncthreads();
  int n2 = blockIdx.x * 32 + ty, k2 = blockIdx.y * 32 + tx;
  T[(size_t)n2 * K + k2] = f2bf(tile[tx][ty]);
}

// ---------- 256x256 bf16 GEMM, BK=32, 4-deep LDS ring, counted vmcnt ----------
// C[M,N] = A[M,K] @ BT[N,K]^T ; bf16 in/out, fp32 acc.
// LDS chunk-swizzle: chunk' = chunk ^ ((row>>1)&3), applied via pre-swizzled
// global source (gload_lds dest stays linear = base + lane*16) + swizzled read.
__global__ __launch_bounds__(512, 2)
void gemm256(const unsigned short* __restrict__ A, const unsigned short* __restrict__ BT,
             unsigned short* __restrict__ C, int M, int N, int K, int ntile){
  __shared__ unsigned short sA[4][8192];   // 4 x [256 rows][32 bf16]
  __shared__ unsigned short sB[4][8192];
  const int t = threadIdx.x;
  const int lane = t & 63;
  const int w = t >> 6;                     // 0..7
  const int wr = w >> 2, wc = w & 3;        // 2M x 4N waves
  const int mt = blockIdx.x / ntile, nt = blockIdx.x % ntile;
  const int m0 = mt << 8, n0 = nt << 8;
  const int NK = K >> 5;

  // fragment LDS offsets (ushort units), swizzled
  int offA[8], offB[4];
#pragma unroll
  for (int m = 0; m < 8; ++m){
    int row = wr * 128 + m * 16 + (lane & 15);
    offA[m] = row * 32 + (((lane >> 4) ^ ((row >> 1) & 3)) << 3);
  }
#pragma unroll
  for (int n = 0; n < 4; ++n){
    int row = wc * 64 + n * 16 + (lane & 15);
    offB[n] = row * 32 + (((lane >> 4) ^ ((row >> 1) & 3)) << 3);
  }

  // staging precompute: thread t covers rows (t>>2) and (t>>2)+128, chunk (t&3)
  const int srow = t >> 2;
  const int cg8 = (((t & 3) ^ ((srow >> 1) & 3)) << 3);  // swizzled global chunk (elems)
  int ar0 = m0 + srow;        if (ar0 >= M) ar0 = M - 1;
  int ar1 = m0 + 128 + srow;  if (ar1 >= M) ar1 = M - 1;
  const unsigned short* apr0 = A + (size_t)ar0 * K + cg8;
  const unsigned short* apr1 = A + (size_t)ar1 * K + cg8;
  const unsigned short* bpr0 = BT + (size_t)(n0 + srow) * K + cg8;
  const unsigned short* bpr1 = BT + (size_t)(n0 + 128 + srow) * K + cg8;
  const int dst0 = srow * 32 + ((t & 3) << 3);           // linear LDS dst (ushort idx)

#define STAGE0(s) { int _b = (s) & 3; int _k = (s) << 5; \
    gload16(apr0 + _k, &sA[_b][dst0]); \
    gload16(bpr0 + _k, &sB[_b][dst0]); }
#define STAGE1(s) { int _b = (s) & 3; int _k = (s) << 5; \
    gload16(apr1 + _k, &sA[_b][dst0 + 4096]); \
    gload16(bpr1 + _k, &sB[_b][dst0 + 4096]); }

  f32x4 acc[8][4];
#pragma unroll
  for (int i = 0; i < 8; ++i)
#pragma unroll
    for (int j = 0; j < 4; ++j) acc[i][j] = (f32x4){0.f, 0.f, 0.f, 0.f};

  // prologue: stage steps 0,1,2 (12 loads); wait for step0 (oldest 4)
  STAGE0(0); STAGE1(0); STAGE0(1); STAGE1(1); STAGE0(2); STAGE1(2);
  asm volatile("s_waitcnt vmcnt(8)" ::: "memory");
  __builtin_amdgcn_s_barrier();
  __builtin_amdgcn_sched_barrier(0);

  for (int ks = 0; ks < NK; ++ks){
    const int buf = ks & 3;
    const unsigned short* pa = &sA[buf][0];
    const unsigned short* pb = &sB[buf][0];
    // ---- phase A: read A m0..3 + B n0..3, stage half, 16 MFMA ----
    s16x8 av[4], bv[4];
#pragma unroll
    for (int i = 0; i < 4; ++i) av[i] = *(const s16x8*)(pa + offA[i]);
#pragma unroll
    for (int i = 0; i < 4; ++i) bv[i] = *(const s16x8*)(pb + offB[i]);
    if (ks + 3 < NK) STAGE0(ks + 3);
    __builtin_amdgcn_s_barrier();
    __builtin_amdgcn_sched_barrier(0);
    __builtin_amdgcn_s_setprio(1);
#pragma unroll
    for (int mi = 0; mi < 4; ++mi)
#pragma unroll
      for (int ni = 0; ni < 4; ++ni)
        acc[mi][ni] = __builtin_amdgcn_mfma_f32_16x16x32_bf16(av[mi], bv[ni], acc[mi][ni], 0, 0, 0);
    __builtin_amdgcn_s_setprio(0);
    __builtin_amdgcn_s_barrier();
    __builtin_amdgcn_sched_barrier(0);
    // ---- phase B: read A m4..7, stage half, counted vmcnt, 16 MFMA ----
    s16x8 av2[4];
#pragma unroll
    for (int i = 0; i < 4; ++i) av2[i] = *(const s16x8*)(pa + offA[4 + i]);
    if (ks + 3 < NK) STAGE1(ks + 3);
    if (ks < NK - 3)      { asm volatile("s_waitcnt vmcnt(8)" ::: "memory"); }
    else if (ks == NK - 3){ asm volatile("s_waitcnt vmcnt(4)" ::: "memory"); }
    else if (ks == NK - 2){ asm volatile("s_waitcnt vmcnt(0)" ::: "memory"); }
    __builtin_amdgcn_s_barrier();
    __builtin_amdgcn_sched_barrier(0);
    __builtin_amdgcn_s_setprio(1);
#pragma unroll
    for (int mi = 0; mi < 4; ++mi)
#pragma unroll
      for (int ni = 0; ni < 4; ++ni)
        acc[4 + mi][ni] = __builtin_amdgcn_mfma_f32_16x16x32_bf16(av2[mi], bv[ni], acc[4 + mi][ni], 0, 0, 0);
    __builtin_amdgcn_s_setprio(0);
    __builtin_amdgcn_s_barrier();
    __builtin_amdgcn_sched_barrier(0);
  }
#undef STAGE0
#undef STAGE1

  // epilogue: C/D layout col=lane&15, row=(lane>>4)*4+r
#pragma unroll
  for (int mi = 0; mi < 8; ++mi)
#pragma unroll
    for (int ni = 0; ni < 4; ++ni){
      int col = n0 + wc * 64 + ni * 16 + (lane & 15);
#pragma unroll
      for (int r = 0; r < 4; ++r){
        int row = m0 + wr * 128 + mi * 16 + ((lane >> 4) << 2) + r;
        if (row < M) C[(size_t)row * N + col] = f2bf(acc[mi][ni][r]);
      }
    }
}

// ---------- per-node alpha_src/alpha_dst from bf16 xw ----------
template<int C>                       // block = C/2 threads
__global__ void k_alpha(const unsigned short* __restrict__ xw, const float* __restrict__ a_src,
                        const float* __restrict__ a_dst, float* __restrict__ asrc,
                        float* __restrict__ adst){
  const int n = blockIdx.x, t = threadIdx.x;
  constexpr int W = C / 8;
  const int head = (t * 8) / C;
  const int c0 = (t * 8) % C;
  s16x8 v = *(const s16x8*)(xw + (size_t)n * 4 * C + t * 8);
  float4 s0 = *(const float4*)(a_src + head * C + c0);
  float4 s1 = *(const float4*)(a_src + head * C + c0 + 4);
  float4 d0 = *(const float4*)(a_dst + head * C + c0);
  float4 d1 = *(const float4*)(a_dst + head * C + c0 + 4);
  float f[8];
#pragma unroll
  for (int j = 0; j < 8; ++j) f[j] = bf2f((unsigned short)v[j]);
  float ps = f[0]*s0.x + f[1]*s0.y + f[2]*s0.z + f[3]*s0.w
           + f[4]*s1.x + f[5]*s1.y + f[6]*s1.z + f[7]*s1.w;
  float pd = f[0]*d0.x + f[1]*d0.y + f[2]*d0.z + f[3]*d0.w
           + f[4]*d1.x + f[5]*d1.y + f[6]*d1.z + f[7]*d1.w;
#pragma unroll
  for (int off = W / 2; off; off >>= 1){
    ps += __shfl_xor(ps, off);
    pd += __shfl_xor(pd, off);
  }
  if ((t & (W - 1)) == 0){
    asrc[n * 4 + head] = ps;
    adst[n * 4 + head] = pd;
  }
}

// ---------- CSR build ----------
__global__ void k_count(const int* __restrict__ ei, int* __restrict__ counts){
  int e = blockIdx.x * blockDim.x + threadIdx.x;
  if (e >= NETOT) return;
  int d = (e < NE) ? ei[NE + e] : (e - NE);
  atomicAdd(&counts[d], 1);
}
__global__ void k_scan(const int* __restrict__ counts, int* __restrict__ row_ptr,
                       int* __restrict__ cursor){
  __shared__ int lds[1024];
  int t = threadIdx.x;
  int base = 0;
  for (int c0 = 0; c0 < NN; c0 += 1024){
    int i = c0 + t;
    int v = (i < NN) ? counts[i] : 0;
    __syncthreads();
    lds[t] = v;
    __syncthreads();
    for (int off = 1; off < 1024; off <<= 1){
      int x = (t >= off) ? lds[t - off] : 0;
      __syncthreads();
      lds[t] += x;
      __syncthreads();
    }
    int excl = base + lds[t] - v;
    if (i < NN){ row_ptr[i] = excl; cursor[i] = excl; }
    base += lds[1023];
  }
  if (t == 0) row_ptr[NN] = base;
}
__global__ void k_scatter(const int* __restrict__ ei, int* __restrict__ cursor,
                          int* __restrict__ csr_src){
  int e = blockIdx.x * blockDim.x + threadIdx.x;
  if (e >= NETOT) return;
  int s, d;
  if (e < NE){ s = ei[e]; d = ei[NE + e]; } else { s = d = e - NE; }
  int pos = atomicAdd(&cursor[d], 1);
  csr_src[pos] = s;
}

// ---------- fused segment softmax: one wave per node, no atomics ----------
__global__ void k_edge(const int* __restrict__ rp, const int* __restrict__ csrc,
                       const float* __restrict__ asrc, const float* __restrict__ adst,
                       float* __restrict__ ex, float* __restrict__ den){
  int n = blockIdx.x * 4 + (threadIdx.x >> 6);
  if (n >= NN) return;
  int lane = threadIdx.x & 63;
  int beg = rp[n], end = rp[n + 1];
  float4 ad = ((const float4*)adst)[n];
  float mx0 = -1e30f, mx1 = -1e30f, mx2 = -1e30f, mx3 = -1e30f;
  for (int i = beg + lane; i < end; i += 64){
    int s = csrc[i];
    float4 as = ((const float4*)asrc)[s];
    float v0 = as.x + ad.x; v0 = v0 > 0.f ? v0 : 0.2f * v0; mx0 = fmaxf(mx0, v0);
    float v1 = as.y + ad.y; v1 = v1 > 0.f ? v1 : 0.2f * v1; mx1 = fmaxf(mx1, v1);
    float v2 = as.z + ad.z; v2 = v2 > 0.f ? v2 : 0.2f * v2; mx2 = fmaxf(mx2, v2);
    float v3 = as.w + ad.w; v3 = v3 > 0.f ? v3 : 0.2f * v3; mx3 = fmaxf(mx3, v3);
  }
#pragma unroll
  for (int off = 32; off; off >>= 1){
    mx0 = fmaxf(mx0, __shfl_xor(mx0, off));
    mx1 = fmaxf(mx1, __shfl_xor(mx1, off));
    mx2 = fmaxf(mx2, __shfl_xor(mx2, off));
    mx3 = fmaxf(mx3, __shfl_xor(mx3, off));
  }
  float s0 = 0.f, s1 = 0.f, s2 = 0.f, s3 = 0.f;
  for (int i = beg + lane; i < end; i += 64){
    int s = csrc[i];
    float4 as = ((const float4*)asrc)[s];
    float v0 = as.x + ad.x; v0 = v0 > 0.f ? v0 : 0.2f * v0;
    float v1 = as.y + ad.y; v1 = v1 > 0.f ? v1 : 0.2f * v1;
    float v2 = as.z + ad.z; v2 = v2 > 0.f ? v2 : 0.2f * v2;
    float v3 = as.w + ad.w; v3 = v3 > 0.f ? v3 : 0.2f * v3;
    float e0 = __expf(v0 - mx0), e1 = __expf(v1 - mx1);
    float e2 = __expf(v2 - mx2), e3 = __expf(v3 - mx3);
    s0 += e0; s1 += e1; s2 += e2; s3 += e3;
    ((float4*)ex)[i] = make_float4(e0, e1, e2, e3);
  }
#pragma unroll
  for (int off = 32; off; off >>= 1){
    s0 += __shfl_xor(s0, off);
    s1 += __shfl_xor(s1, off);
    s2 += __shfl_xor(s2, off);
    s3 += __shfl_xor(s3, off);
  }
  if (lane == 0) ((float4*)den)[n] = make_float4(s0, s1, s2, s3);
}

// ---------- aggregation from bf16 xw (ex indexed by CSR position) ----------
template<int C, bool BF16OUT>         // block = C/2, one block per node
__global__ void k_agg(const unsigned short* __restrict__ xw, const int* __restrict__ row_ptr,
                      const int* __restrict__ csr_src,
                      const float* __restrict__ ex, const float* __restrict__ den,
                      const float* __restrict__ bias, void* __restrict__ outp){
  const int n = blockIdx.x, t = threadIdx.x;
  float4 dv = ((const float4*)den)[n];
  float rd[4] = {1.f / (dv.x + 1e-16f), 1.f / (dv.y + 1e-16f),
                 1.f / (dv.z + 1e-16f), 1.f / (dv.w + 1e-16f)};
  float acc[4][2] = {};
  int beg = row_ptr[n], end = row_ptr[n + 1];
  for (int i = beg; i < end; ++i){
    int s = csr_src[i];
    float4 exv = ((const float4*)ex)[i];
    float al[4] = {exv.x * rd[0], exv.y * rd[1], exv.z * rd[2], exv.w * rd[3]};
    const unsigned short* sb = xw + (size_t)s * 4 * C + 2 * t;
#pragma unroll
    for (int h = 0; h < 4; ++h){
      ushort2 v = *(const ushort2*)(sb + h * C);
      acc[h][0] += al[h] * bf2f(v.x);
      acc[h][1] += al[h] * bf2f(v.y);
    }
  }
  float o0 = 0.25f * (acc[0][0] + acc[1][0] + acc[2][0] + acc[3][0]) + bias[2 * t];
  float o1 = 0.25f * (acc[0][1] + acc[1][1] + acc[2][1] + acc[3][1]) + bias[2 * t + 1];
  if (BF16OUT){
    ushort2 o; o.x = f2bf(o0); o.y = f2bf(o1);
    ((ushort2*)outp)[(size_t)n * (C / 2) + t] = o;
  } else {
    ((float2*)outp)[(size_t)n * (C / 2) + t] = make_float2(o0, o1);
  }
}

// ---------- pooling ----------
__global__ void k_pool(const float* __restrict__ h2, const int* __restrict__ batch,
                       float* __restrict__ sums, int* __restrict__ cnt){
  int n0 = blockIdx.x * 64;
  int t = threadIdx.x;
  int nend = n0 + 64; if (nend > NN) nend = NN;
  int cur = batch[n0];
  float acc = 0.f; int run = 0;
  for (int n = n0; n < nend; ++n){
    int b = batch[n];
    if (b != cur){
      atomicAdd(&sums[cur * 256 + t], acc);
      if (t == 0) atomicAdd(&cnt[cur], run);
      acc = 0.f; run = 0; cur = b;
    }
    acc += h2[(size_t)n * 256 + t];
    run++;
  }
  atomicAdd(&sums[cur * 256 + t], acc);
  if (t == 0) atomicAdd(&cnt[cur], run);
}

__global__ void k_fc(const float* __restrict__ sums, const int* __restrict__ cnt,
                     const float* __restrict__ fcW, const float* __restrict__ fcb,
                     float* __restrict__ out){
  int b = blockIdx.x, t = threadIdx.x;
  int c = cnt[b]; if (c < 1) c = 1;
  float inv = 1.f / (float)c;
  float v = sums[b * 256 + t] * inv;
  float p0 = v * fcW[t * 2];
  float p1 = v * fcW[t * 2 + 1];
#pragma unroll
  for (int off = 32; off; off >>= 1){
    p0 += __shfl_xor(p0, off);
    p1 += __shfl_xor(p1, off);
  }
  __shared__ float r0[4], r1[4];
  if ((t & 63) == 0){ r0[t >> 6] = p0; r1[t >> 6] = p1; }
  __syncthreads();
  if (t == 0){
    out[b * 2 + 0] = r0[0] + r0[1] + r0[2] + r0[3] + fcb[0];
    out[b * 2 + 1] = r1[0] + r1[1] + r1[2] + r1[3] + fcb[1];
  }
}

extern "C" void kernel_launch(void* const* d_in, const int* in_sizes, int n_in,
                              void* d_out, int out_size, void* d_ws, size_t ws_size,
                              hipStream_t stream){
  const float* x      = (const float*)d_in[0];
  const int*   ei     = (const int*)d_in[1];
  const int*   batch  = (const int*)d_in[2];
  const float* W1     = (const float*)d_in[3];
  const float* a_src1 = (const float*)d_in[4];
  const float* a_dst1 = (const float*)d_in[5];
  const float* b1     = (const float*)d_in[6];
  const float* W2     = (const float*)d_in[7];
  const float* a_src2 = (const float*)d_in[8];
  const float* a_dst2 = (const float*)d_in[9];
  const float* b2     = (const float*)d_in[10];
  const float* fcW    = (const float*)d_in[11];
  const float* fcb    = (const float*)d_in[12];
  float* out = (float*)d_out;
  (void)in_sizes; (void)n_in; (void)out_size; (void)ws_size;

  char* ws = (char*)d_ws;
  size_t off = 0;
  auto take = [&](size_t bytes) -> char* {
    char* p = ws + off;
    off += (bytes + 255) & ~(size_t)255;
    return p;
  };
  char* slab0 = take(81920000);                             // xw1 bf16 [20000,2048]; aliased by xw2
  unsigned short* xw1 = (unsigned short*)slab0;
  unsigned short* xw2 = (unsigned short*)slab0;
  unsigned short* x_bf  = (unsigned short*)take(30720000);  // [20000,768] bf16
  unsigned short* h1_bf = (unsigned short*)take(20480000);  // [20000,512] bf16
  float*          h2    = (float*)take(20480000);           // [20000,256] f32
  unsigned short* W1T = (unsigned short*)take(3145728);
  unsigned short* W2T = (unsigned short*)take(1048576);
  float* asrc   = (float*)take(320000);
  float* adst   = (float*)take(320000);
  float* den    = (float*)take(320000);
  float* ex     = (float*)take((size_t)NETOT * 16);
  int* counts   = (int*)take(80004);
  int* row_ptr  = (int*)take(80004);
  int* cursor   = (int*)take(80004);
  int* csr_src  = (int*)take(720000);
  float* sums   = (float*)take(131072);
  int* cnt      = (int*)take(512);

  const int egrid = (NETOT + 255) / 256;

  // ---- CSR (shared by both layers) ----
  hipMemsetAsync(counts, 0, NN * 4, stream);
  k_count<<<egrid, 256, 0, stream>>>(ei, counts);
  k_scan<<<1, 1024, 0, stream>>>(counts, row_ptr, cursor);
  k_scatter<<<egrid, 256, 0, stream>>>(ei, cursor, csr_src);

  // ---- layer 1 ----
  k_cvt<<<(3840000 + 255) / 256, 256, 0, stream>>>(x, x_bf, 3840000);
  k_tcvt<<<dim3(2048 / 32, 768 / 32), dim3(32, 32), 0, stream>>>(W1, W1T, 768, 2048);
  gemm256<<<79 * 8, 512, 0, stream>>>(x_bf, W1T, xw1, NN, 2048, 768, 8);
  k_alpha<512><<<NN, 256, 0, stream>>>(xw1, a_src1, a_dst1, asrc, adst);
  k_edge<<<(NN + 3) / 4, 256, 0, stream>>>(row_ptr, csr_src, asrc, adst, ex, den);
  k_agg<512, true><<<NN, 256, 0, stream>>>(xw1, row_ptr, csr_src, ex, den, b1, h1_bf);

  // ---- layer 2 ----
  k_tcvt<<<dim3(1024 / 32, 512 / 32), dim3(32, 32), 0, stream>>>(W2, W2T, 512, 1024);
  gemm256<<<79 * 4, 512, 0, stream>>>(h1_bf, W2T, xw2, NN, 1024, 512, 4);
  k_alpha<256><<<NN, 128, 0, stream>>>(xw2, a_src2, a_dst2, asrc, adst);
  k_edge<<<(NN + 3) / 4, 256, 0, stream>>>(row_ptr, csr_src, asrc, adst, ex, den);
  k_agg<256, false><<<NN, 128, 0, stream>>>(xw2, row_ptr, csr_src, ex, den, b2, h2);

  // ---- pool + fc ----
  hipMemsetAsync(sums, 0, 131072, stream);
  hipMemsetAsync(cnt, 0, 512, stream);
  k_pool<<<(NN + 63) / 64, 256, 0, stream>>>(h2, batch, sums, cnt);
  k_fc<<<NB, 256, 0, stream>>>(sums, cnt, fcW, fcb, out);
}

// Round 4
// 540.194 us; speedup vs baseline: 1.8364x; 1.0159x over previous
//
#include <hip/hip_runtime.h>

#define NN    20000
#define NE    160000
#define NETOT 180000
#define NB    128

typedef __attribute__((ext_vector_type(4))) float f32x4;
typedef __attribute__((ext_vector_type(8))) short s16x8;

__device__ __forceinline__ unsigned short f2bf(float f){
  unsigned u = __float_as_uint(f);
  return (unsigned short)((u + 0x7FFFu + ((u >> 16) & 1u)) >> 16);
}
__device__ __forceinline__ float bf2f(unsigned short h){
  return __uint_as_float(((unsigned)h) << 16);
}
__device__ __forceinline__ void gload16(const void* g, void* l){
  __builtin_amdgcn_global_load_lds((const __attribute__((address_space(1))) void*)g,
                                   (__attribute__((address_space(3))) void*)l, 16, 0, 0);
}

// ---------- f32 -> bf16 convert ----------
__global__ void k_cvt(const float* __restrict__ in, unsigned short* __restrict__ outp, int n4){
  int i = blockIdx.x * blockDim.x + threadIdx.x;
  if (i >= n4) return;
  float4 v = ((const float4*)in)[i];
  ushort4 h;
  h.x = f2bf(v.x); h.y = f2bf(v.y); h.z = f2bf(v.z); h.w = f2bf(v.w);
  ((ushort4*)outp)[i] = h;
}

// ---------- transpose + convert: W[K][N] -> WT[N][K] bf16 ----------
__global__ void k_tcvt(const float* __restrict__ W, unsigned short* __restrict__ T, int K, int N){
  __shared__ float tile[32][33];
  int tx = threadIdx.x, ty = threadIdx.y;
  int n = blockIdx.x * 32 + tx, k = blockIdx.y * 32 + ty;
  tile[ty][tx] = W[(size_t)k * N + n];
  __syncthreads();
  int n2 = blockIdx.x * 32 + ty, k2 = blockIdx.y * 32 + tx;
  T[(size_t)n2 * K + k2] = f2bf(tile[tx][ty]);
}

// ---------- 128x256 bf16 GEMM, BK=32, double-buffer, 2 blocks/CU ----------
// C[M,N] = A[M,K] @ BT[N,K]^T; bf16 in/out, fp32 acc. 4 waves, wave = 64x128.
// LDS chunk-swizzle chunk^=( (row>>1)&3 ) via pre-swizzled global source
// (gload_lds dest linear) + swizzled ds_read. Epilogue repacks C-tile in LDS
// for coalesced 16B stores (kills write-allocate RMW fetch).
__global__ __launch_bounds__(256, 2)
void gemm_bf16(const unsigned short* __restrict__ A, const unsigned short* __restrict__ BT,
               unsigned short* __restrict__ C, int M, int N, int K, int ntile){
  __shared__ unsigned short lds[24576];       // 2 bufs x (A 4096 + B 8192 ushorts) = 48 KB
  const int t = threadIdx.x;
  const int lane = t & 63;
  const int w = t >> 6;                       // 0..3
  const int wr = w >> 1, wc = w & 1;          // 2M x 2N waves, wave out 64x128
  const int mt = blockIdx.x / ntile, nt = blockIdx.x % ntile;
  const int m0 = mt << 7, n0 = nt << 8;
  const int NK = K >> 5;

  // fragment LDS offsets (ushort units), swizzled
  int offA[4], offB[8];
#pragma unroll
  for (int mi = 0; mi < 4; ++mi){
    int row = wr * 64 + mi * 16 + (lane & 15);
    offA[mi] = row * 32 + (((lane >> 4) ^ ((row >> 1) & 3)) << 3);
  }
#pragma unroll
  for (int ni = 0; ni < 8; ++ni){
    int row = wc * 128 + ni * 16 + (lane & 15);
    offB[ni] = 4096 + row * 32 + (((lane >> 4) ^ ((row >> 1) & 3)) << 3);
  }

  // staging: per-wave-linear LDS dst (base + lane*16); source chunk pre-swizzled
  const unsigned short* srcA[2]; int dstA[2];
#pragma unroll
  for (int j = 0; j < 2; ++j){
    int rA = w * 32 + j * 16 + (lane >> 2);
    int gr = m0 + rA; if (gr >= M) gr = M - 1;
    srcA[j] = A + (size_t)gr * K + (((lane & 3) ^ ((rA >> 1) & 3)) << 3);
    dstA[j] = w * 1024 + j * 512 + lane * 8;
  }
  const unsigned short* srcB[4]; int dstB[4];
#pragma unroll
  for (int j = 0; j < 4; ++j){
    int rB = w * 64 + j * 16 + (lane >> 2);
    srcB[j] = BT + (size_t)(n0 + rB) * K + (((lane & 3) ^ ((rB >> 1) & 3)) << 3);
    dstB[j] = 4096 + w * 2048 + j * 512 + lane * 8;
  }

#define STAGE(ks, bo) { int _k = (ks) << 5; \
    gload16(srcA[0] + _k, &lds[(bo) + dstA[0]]); \
    gload16(srcA[1] + _k, &lds[(bo) + dstA[1]]); \
    gload16(srcB[0] + _k, &lds[(bo) + dstB[0]]); \
    gload16(srcB[1] + _k, &lds[(bo) + dstB[1]]); \
    gload16(srcB[2] + _k, &lds[(bo) + dstB[2]]); \
    gload16(srcB[3] + _k, &lds[(bo) + dstB[3]]); }

  f32x4 acc[4][8];
#pragma unroll
  for (int i = 0; i < 4; ++i)
#pragma unroll
    for (int j = 0; j < 8; ++j) acc[i][j] = (f32x4){0.f, 0.f, 0.f, 0.f};

  STAGE(0, 0);
  asm volatile("s_waitcnt vmcnt(0)" ::: "memory");
  __builtin_amdgcn_sched_barrier(0);
  __builtin_amdgcn_s_barrier();
  __builtin_amdgcn_sched_barrier(0);

  for (int ks = 0; ks < NK; ++ks){
    const int bo = (ks & 1) * 12288;
    s16x8 av[4], bv[8];
#pragma unroll
    for (int i = 0; i < 4; ++i) av[i] = *(const s16x8*)&lds[bo + offA[i]];
#pragma unroll
    for (int i = 0; i < 8; ++i) bv[i] = *(const s16x8*)&lds[bo + offB[i]];
    if (ks + 1 < NK) STAGE(ks + 1, 12288 - bo);
    __builtin_amdgcn_s_setprio(1);
#pragma unroll
    for (int mi = 0; mi < 4; ++mi)
#pragma unroll
      for (int ni = 0; ni < 8; ++ni)
        acc[mi][ni] = __builtin_amdgcn_mfma_f32_16x16x32_bf16(av[mi], bv[ni], acc[mi][ni], 0, 0, 0);
    __builtin_amdgcn_s_setprio(0);
    asm volatile("s_waitcnt vmcnt(0)" ::: "memory");
    __builtin_amdgcn_sched_barrier(0);
    __builtin_amdgcn_s_barrier();
    __builtin_amdgcn_sched_barrier(0);
  }
#undef STAGE

  // ---- epilogue: repack C through LDS (32 KB per half), coalesced 16B stores ----
  // physical byte = (rl*512 + col*2) ^ (((rl>>2)&3)<<5)  -> conflict-free both sides
#pragma unroll
  for (int h = 0; h < 2; ++h){
    if (wr == h){
#pragma unroll
      for (int mi = 0; mi < 4; ++mi)
#pragma unroll
        for (int ni = 0; ni < 8; ++ni)
#pragma unroll
          for (int r = 0; r < 4; ++r){
            int rl = mi * 16 + ((lane >> 4) << 2) + r;       // 0..63
            int col = wc * 128 + ni * 16 + (lane & 15);      // 0..255
            int byte = (rl * 512 + col * 2) ^ (((rl >> 2) & 3) << 5);
            *(unsigned short*)((char*)lds + byte) = f2bf(acc[mi][ni][r]);
          }
    }
    __syncthreads();
#pragma unroll
    for (int it = 0; it < 8; ++it){
      int idx = it * 256 + t;
      int rl = idx >> 5, c16 = idx & 31;
      int byte = (rl * 512 + c16 * 16) ^ (((rl >> 2) & 3) << 5);
      s16x8 v = *(const s16x8*)((const char*)lds + byte);
      int grow = m0 + h * 64 + rl;
      if (grow < M)
        *(s16x8*)(C + (size_t)grow * N + n0 + c16 * 8) = v;
    }
    __syncthreads();
  }
}

// ---------- per-node alpha_src/alpha_dst from bf16 xw ----------
template<int C>                       // block = C/2 threads
__global__ void k_alpha(const unsigned short* __restrict__ xw, const float* __restrict__ a_src,
                        const float* __restrict__ a_dst, float* __restrict__ asrc,
                        float* __restrict__ adst){
  const int n = blockIdx.x, t = threadIdx.x;
  constexpr int W = C / 8;
  const int head = (t * 8) / C;
  const int c0 = (t * 8) % C;
  s16x8 v = *(const s16x8*)(xw + (size_t)n * 4 * C + t * 8);
  float4 s0 = *(const float4*)(a_src + head * C + c0);
  float4 s1 = *(const float4*)(a_src + head * C + c0 + 4);
  float4 d0 = *(const float4*)(a_dst + head * C + c0);
  float4 d1 = *(const float4*)(a_dst + head * C + c0 + 4);
  float f[8];
#pragma unroll
  for (int j = 0; j < 8; ++j) f[j] = bf2f((unsigned short)v[j]);
  float ps = f[0]*s0.x + f[1]*s0.y + f[2]*s0.z + f[3]*s0.w
           + f[4]*s1.x + f[5]*s1.y + f[6]*s1.z + f[7]*s1.w;
  float pd = f[0]*d0.x + f[1]*d0.y + f[2]*d0.z + f[3]*d0.w
           + f[4]*d1.x + f[5]*d1.y + f[6]*d1.z + f[7]*d1.w;
#pragma unroll
  for (int off = W / 2; off; off >>= 1){
    ps += __shfl_xor(ps, off);
    pd += __shfl_xor(pd, off);
  }
  if ((t & (W - 1)) == 0){
    asrc[n * 4 + head] = ps;
    adst[n * 4 + head] = pd;
  }
}

// ---------- CSR build ----------
__global__ void k_count(const int* __restrict__ ei, int* __restrict__ counts){
  int e = blockIdx.x * blockDim.x + threadIdx.x;
  if (e >= NETOT) return;
  int d = (e < NE) ? ei[NE + e] : (e - NE);
  atomicAdd(&counts[d], 1);
}
__global__ void k_scan(const int* __restrict__ counts, int* __restrict__ row_ptr,
                       int* __restrict__ cursor){
  __shared__ int lds[1024];
  int t = threadIdx.x;
  int base = 0;
  for (int c0 = 0; c0 < NN; c0 += 1024){
    int i = c0 + t;
    int v = (i < NN) ? counts[i] : 0;
    __syncthreads();
    lds[t] = v;
    __syncthreads();
    for (int off = 1; off < 1024; off <<= 1){
      int x = (t >= off) ? lds[t - off] : 0;
      __syncthreads();
      lds[t] += x;
      __syncthreads();
    }
    int excl = base + lds[t] - v;
    if (i < NN){ row_ptr[i] = excl; cursor[i] = excl; }
    base += lds[1023];
  }
  if (t == 0) row_ptr[NN] = base;
}
__global__ void k_scatter(const int* __restrict__ ei, int* __restrict__ cursor,
                          int* __restrict__ csr_src){
  int e = blockIdx.x * blockDim.x + threadIdx.x;
  if (e >= NETOT) return;
  int s, d;
  if (e < NE){ s = ei[e]; d = ei[NE + e]; } else { s = d = e - NE; }
  int pos = atomicAdd(&cursor[d], 1);
  csr_src[pos] = s;
}

// ---------- fused segment softmax: one wave per node, no atomics ----------
__global__ void k_edge(const int* __restrict__ rp, const int* __restrict__ csrc,
                       const float* __restrict__ asrc, const float* __restrict__ adst,
                       float* __restrict__ ex, float* __restrict__ den){
  int n = blockIdx.x * 4 + (threadIdx.x >> 6);
  if (n >= NN) return;
  int lane = threadIdx.x & 63;
  int beg = rp[n], end = rp[n + 1];
  float4 ad = ((const float4*)adst)[n];
  float mx0 = -1e30f, mx1 = -1e30f, mx2 = -1e30f, mx3 = -1e30f;
  for (int i = beg + lane; i < end; i += 64){
    int s = csrc[i];
    float4 as = ((const float4*)asrc)[s];
    float v0 = as.x + ad.x; v0 = v0 > 0.f ? v0 : 0.2f * v0; mx0 = fmaxf(mx0, v0);
    float v1 = as.y + ad.y; v1 = v1 > 0.f ? v1 : 0.2f * v1; mx1 = fmaxf(mx1, v1);
    float v2 = as.z + ad.z; v2 = v2 > 0.f ? v2 : 0.2f * v2; mx2 = fmaxf(mx2, v2);
    float v3 = as.w + ad.w; v3 = v3 > 0.f ? v3 : 0.2f * v3; mx3 = fmaxf(mx3, v3);
  }
#pragma unroll
  for (int off = 32; off; off >>= 1){
    mx0 = fmaxf(mx0, __shfl_xor(mx0, off));
    mx1 = fmaxf(mx1, __shfl_xor(mx1, off));
    mx2 = fmaxf(mx2, __shfl_xor(mx2, off));
    mx3 = fmaxf(mx3, __shfl_xor(mx3, off));
  }
  float s0 = 0.f, s1 = 0.f, s2 = 0.f, s3 = 0.f;
  for (int i = beg + lane; i < end; i += 64){
    int s = csrc[i];
    float4 as = ((const float4*)asrc)[s];
    float v0 = as.x + ad.x; v0 = v0 > 0.f ? v0 : 0.2f * v0;
    float v1 = as.y + ad.y; v1 = v1 > 0.f ? v1 : 0.2f * v1;
    float v2 = as.z + ad.z; v2 = v2 > 0.f ? v2 : 0.2f * v2;
    float v3 = as.w + ad.w; v3 = v3 > 0.f ? v3 : 0.2f * v3;
    float e0 = __expf(v0 - mx0), e1 = __expf(v1 - mx1);
    float e2 = __expf(v2 - mx2), e3 = __expf(v3 - mx3);
    s0 += e0; s1 += e1; s2 += e2; s3 += e3;
    ((float4*)ex)[i] = make_float4(e0, e1, e2, e3);
  }
#pragma unroll
  for (int off = 32; off; off >>= 1){
    s0 += __shfl_xor(s0, off);
    s1 += __shfl_xor(s1, off);
    s2 += __shfl_xor(s2, off);
    s3 += __shfl_xor(s3, off);
  }
  if (lane == 0) ((float4*)den)[n] = make_float4(s0, s1, s2, s3);
}

// ---------- aggregation: thread owns one head's 8 cols, 16B gathers ----------
template<int C, bool BF16OUT>         // block = C/2 threads, one block per node
__global__ void k_agg(const unsigned short* __restrict__ xw, const int* __restrict__ row_ptr,
                      const int* __restrict__ csr_src,
                      const float* __restrict__ ex, const float* __restrict__ den,
                      const float* __restrict__ bias, void* __restrict__ outp){
  const int n = blockIdx.x, t = threadIdx.x;
  constexpr int LPH = C / 8;          // threads per head
  const int h = t / LPH, c0 = (t % LPH) * 8;
  __shared__ float red[4][C];
  float rdh = 1.f / (den[n * 4 + h] + 1e-16f);
  float acc[8] = {};
  int beg = row_ptr[n], end = row_ptr[n + 1];
  const unsigned short* xwh = xw + h * C + c0;
  for (int i = beg; i < end; ++i){
    int s = csr_src[i];
    float aa = ex[i * 4 + h] * rdh;
    s16x8 v = *(const s16x8*)(xwh + (size_t)s * 4 * C);
#pragma unroll
    for (int j = 0; j < 8; ++j) acc[j] += aa * bf2f((unsigned short)v[j]);
  }
#pragma unroll
  for (int j = 0; j < 8; ++j) red[h][c0 + j] = acc[j];
  __syncthreads();
  if (t < LPH){
    int cc = t * 8;
    float o[8];
#pragma unroll
    for (int j = 0; j < 8; ++j)
      o[j] = 0.25f * (red[0][cc + j] + red[1][cc + j] + red[2][cc + j] + red[3][cc + j])
           + bias[cc + j];
    if (BF16OUT){
      union { unsigned short u[8]; s16x8 v; } pk;
#pragma unroll
      for (int j = 0; j < 8; ++j) pk.u[j] = f2bf(o[j]);
      *(s16x8*)((unsigned short*)outp + (size_t)n * C + cc) = pk.v;
    } else {
      float* op = (float*)outp + (size_t)n * C + cc;
      ((float4*)op)[0] = make_float4(o[0], o[1], o[2], o[3]);
      ((float4*)op)[1] = make_float4(o[4], o[5], o[6], o[7]);
    }
  }
}

// ---------- pooling ----------
__global__ void k_pool(const float* __restrict__ h2, const int* __restrict__ batch,
                       float* __restrict__ sums, int* __restrict__ cnt){
  int n0 = blockIdx.x * 64;
  int t = threadIdx.x;
  int nend = n0 + 64; if (nend > NN) nend = NN;
  int cur = batch[n0];
  float acc = 0.f; int run = 0;
  for (int n = n0; n < nend; ++n){
    int b = batch[n];
    if (b != cur){
      atomicAdd(&sums[cur * 256 + t], acc);
      if (t == 0) atomicAdd(&cnt[cur], run);
      acc = 0.f; run = 0; cur = b;
    }
    acc += h2[(size_t)n * 256 + t];
    run++;
  }
  atomicAdd(&sums[cur * 256 + t], acc);
  if (t == 0) atomicAdd(&cnt[cur], run);
}

__global__ void k_fc(const float* __restrict__ sums, const int* __restrict__ cnt,
                     const float* __restrict__ fcW, const float* __restrict__ fcb,
                     float* __restrict__ out){
  int b = blockIdx.x, t = threadIdx.x;
  int c = cnt[b]; if (c < 1) c = 1;
  float inv = 1.f / (float)c;
  float v = sums[b * 256 + t] * inv;
  float p0 = v * fcW[t * 2];
  float p1 = v * fcW[t * 2 + 1];
#pragma unroll
  for (int off = 32; off; off >>= 1){
    p0 += __shfl_xor(p0, off);
    p1 += __shfl_xor(p1, off);
  }
  __shared__ float r0[4], r1[4];
  if ((t & 63) == 0){ r0[t >> 6] = p0; r1[t >> 6] = p1; }
  __syncthreads();
  if (t == 0){
    out[b * 2 + 0] = r0[0] + r0[1] + r0[2] + r0[3] + fcb[0];
    out[b * 2 + 1] = r1[0] + r1[1] + r1[2] + r1[3] + fcb[1];
  }
}

extern "C" void kernel_launch(void* const* d_in, const int* in_sizes, int n_in,
                              void* d_out, int out_size, void* d_ws, size_t ws_size,
                              hipStream_t stream){
  const float* x      = (const float*)d_in[0];
  const int*   ei     = (const int*)d_in[1];
  const int*   batch  = (const int*)d_in[2];
  const float* W1     = (const float*)d_in[3];
  const float* a_src1 = (const float*)d_in[4];
  const float* a_dst1 = (const float*)d_in[5];
  const float* b1     = (const float*)d_in[6];
  const float* W2     = (const float*)d_in[7];
  const float* a_src2 = (const float*)d_in[8];
  const float* a_dst2 = (const float*)d_in[9];
  const float* b2     = (const float*)d_in[10];
  const float* fcW    = (const float*)d_in[11];
  const float* fcb    = (const float*)d_in[12];
  float* out = (float*)d_out;
  (void)in_sizes; (void)n_in; (void)out_size; (void)ws_size;

  char* ws = (char*)d_ws;
  size_t off = 0;
  auto take = [&](size_t bytes) -> char* {
    char* p = ws + off;
    off += (bytes + 255) & ~(size_t)255;
    return p;
  };
  char* slab0 = take(81920000);                             // xw1 bf16 [20000,2048]; aliased by xw2
  unsigned short* xw1 = (unsigned short*)slab0;
  unsigned short* xw2 = (unsigned short*)slab0;
  unsigned short* x_bf  = (unsigned short*)take(30720000);  // [20000,768] bf16
  unsigned short* h1_bf = (unsigned short*)take(20480000);  // [20000,512] bf16
  float*          h2    = (float*)take(20480000);           // [20000,256] f32
  unsigned short* W1T = (unsigned short*)take(3145728);
  unsigned short* W2T = (unsigned short*)take(1048576);
  float* asrc   = (float*)take(320000);
  float* adst   = (float*)take(320000);
  float* den    = (float*)take(320000);
  float* ex     = (float*)take((size_t)NETOT * 16);
  int* counts   = (int*)take(80004);
  int* row_ptr  = (int*)take(80004);
  int* cursor   = (int*)take(80004);
  int* csr_src  = (int*)take(720000);
  float* sums   = (float*)take(131072);
  int* cnt      = (int*)take(512);

  const int egrid = (NETOT + 255) / 256;

  // ---- CSR (shared by both layers) ----
  hipMemsetAsync(counts, 0, NN * 4, stream);
  k_count<<<egrid, 256, 0, stream>>>(ei, counts);
  k_scan<<<1, 1024, 0, stream>>>(counts, row_ptr, cursor);
  k_scatter<<<egrid, 256, 0, stream>>>(ei, cursor, csr_src);

  // ---- layer 1 ----
  k_cvt<<<(3840000 + 255) / 256, 256, 0, stream>>>(x, x_bf, 3840000);
  k_tcvt<<<dim3(2048 / 32, 768 / 32), dim3(32, 32), 0, stream>>>(W1, W1T, 768, 2048);
  gemm_bf16<<<157 * 8, 256, 0, stream>>>(x_bf, W1T, xw1, NN, 2048, 768, 8);
  k_alpha<512><<<NN, 256, 0, stream>>>(xw1, a_src1, a_dst1, asrc, adst);
  k_edge<<<(NN + 3) / 4, 256, 0, stream>>>(row_ptr, csr_src, asrc, adst, ex, den);
  k_agg<512, true><<<NN, 256, 0, stream>>>(xw1, row_ptr, csr_src, ex, den, b1, h1_bf);

  // ---- layer 2 ----
  k_tcvt<<<dim3(1024 / 32, 512 / 32), dim3(32, 32), 0, stream>>>(W2, W2T, 512, 1024);
  gemm_bf16<<<157 * 4, 256, 0, stream>>>(h1_bf, W2T, xw2, NN, 1024, 512, 4);
  k_alpha<256><<<NN, 128, 0, stream>>>(xw2, a_src2, a_dst2, asrc, adst);
  k_edge<<<(NN + 3) / 4, 256, 0, stream>>>(row_ptr, csr_src, asrc, adst, ex, den);
  k_agg<256, false><<<NN, 128, 0, stream>>>(xw2, row_ptr, csr_src, ex, den, b2, h2);

  // ---- pool + fc ----
  hipMemsetAsync(sums, 0, 131072, stream);
  hipMemsetAsync(cnt, 0, 512, stream);
  k_pool<<<(NN + 63) / 64, 256, 0, stream>>>(h2, batch, sums, cnt);
  k_fc<<<NB, 256, 0, stream>>>(sums, cnt, fcW, fcb, out);
}

// Round 5
// 517.998 us; speedup vs baseline: 1.9151x; 1.0429x over previous
//
#include <hip/hip_runtime.h>

#define NN    20000
#define NE    160000
#define NETOT 180000
#define NB    128

typedef __attribute__((ext_vector_type(4))) float f32x4;
typedef __attribute__((ext_vector_type(8))) short s16x8;

__device__ __forceinline__ unsigned short f2bf(float f){
  unsigned u = __float_as_uint(f);
  return (unsigned short)((u + 0x7FFFu + ((u >> 16) & 1u)) >> 16);
}
__device__ __forceinline__ float bf2f(unsigned short h){
  return __uint_as_float(((unsigned)h) << 16);
}
__device__ __forceinline__ void gload16(const void* g, void* l){
  __builtin_amdgcn_global_load_lds((const __attribute__((address_space(1))) void*)g,
                                   (__attribute__((address_space(3))) void*)l, 16, 0, 0);
}

// ---------- f32 -> bf16 convert ----------
__global__ void k_cvt(const float* __restrict__ in, unsigned short* __restrict__ outp, int n4){
  int i = blockIdx.x * blockDim.x + threadIdx.x;
  if (i >= n4) return;
  float4 v = ((const float4*)in)[i];
  ushort4 h;
  h.x = f2bf(v.x); h.y = f2bf(v.y); h.z = f2bf(v.z); h.w = f2bf(v.w);
  ((ushort4*)outp)[i] = h;
}

// ---------- va[a][k] = sum_c W[k][h*C+c] * a_{src,dst}[h][c]  (a = h / 4+h) ----------
__global__ void k_va(const float* __restrict__ W, const float* __restrict__ aS,
                     const float* __restrict__ aD, float* __restrict__ va, int K, int C){
  __shared__ float a_s[2048], a_d[2048];
  int t = threadIdx.x;
  int HC = 4 * C;
  for (int i = t; i < HC; i += 256){ a_s[i] = aS[i]; a_d[i] = aD[i]; }
  __syncthreads();
  int k = blockIdx.x * 4 + (t >> 6);
  int lane = t & 63;
  if (k >= K) return;
  float ss[4] = {0.f,0.f,0.f,0.f}, dd[4] = {0.f,0.f,0.f,0.f};
  for (int h = 0; h < 4; ++h)
    for (int c0 = 0; c0 < C; c0 += 64){
      float wv = W[(size_t)k * HC + h * C + c0 + lane];
      ss[h] += wv * a_s[h * C + c0 + lane];
      dd[h] += wv * a_d[h * C + c0 + lane];
    }
#pragma unroll
  for (int off = 32; off; off >>= 1)
#pragma unroll
    for (int h = 0; h < 4; ++h){
      ss[h] += __shfl_xor(ss[h], off);
      dd[h] += __shfl_xor(dd[h], off);
    }
  if (lane == 0)
#pragma unroll
    for (int h = 0; h < 4; ++h){
      va[h * K + k] = ss[h];
      va[(4 + h) * K + k] = dd[h];
    }
}

// ---------- alpha_src/dst[n,h] = sum_k x_bf[n,k] * va[a][k] ----------
template<int K>                          // block 256 = 4 waves, wave per node
__global__ void k_alpha_in(const unsigned short* __restrict__ xf, const float* __restrict__ va,
                           float* __restrict__ asrc, float* __restrict__ adst){
  __shared__ float v_s[8 * K];
  int t = threadIdx.x;
  for (int i = t; i < 8 * K; i += 256) v_s[i] = va[i];
  __syncthreads();
  int n = blockIdx.x * 4 + (t >> 6);
  if (n >= NN) return;
  int lane = t & 63;
  const unsigned short* xr = xf + (size_t)n * K;
  float s[8] = {};
#pragma unroll
  for (int j = 0; j < K / 128; ++j){
    int idx = j * 128 + lane * 2;
    ushort2 xv = *(const ushort2*)(xr + idx);
    float f0 = bf2f(xv.x), f1 = bf2f(xv.y);
#pragma unroll
    for (int a = 0; a < 8; ++a)
      s[a] += f0 * v_s[a * K + idx] + f1 * v_s[a * K + idx + 1];
  }
#pragma unroll
  for (int off = 32; off; off >>= 1)
#pragma unroll
    for (int a = 0; a < 8; ++a) s[a] += __shfl_xor(s[a], off);
  if (lane == 0){
    ((float4*)asrc)[n] = make_float4(s[0], s[1], s[2], s[3]);
    ((float4*)adst)[n] = make_float4(s[4], s[5], s[6], s[7]);
  }
}

// ---------- CSR build ----------
__global__ void k_count(const int* __restrict__ ei, int* __restrict__ counts){
  int e = blockIdx.x * blockDim.x + threadIdx.x;
  if (e >= NETOT) return;
  int d = (e < NE) ? ei[NE + e] : (e - NE);
  atomicAdd(&counts[d], 1);
}
__global__ void k_scan(const int* __restrict__ counts, int* __restrict__ row_ptr,
                       int* __restrict__ cursor){
  __shared__ int lds[1024];
  int t = threadIdx.x;
  int base = 0;
  for (int c0 = 0; c0 < NN; c0 += 1024){
    int i = c0 + t;
    int v = (i < NN) ? counts[i] : 0;
    __syncthreads();
    lds[t] = v;
    __syncthreads();
    for (int off = 1; off < 1024; off <<= 1){
      int x = (t >= off) ? lds[t - off] : 0;
      __syncthreads();
      lds[t] += x;
      __syncthreads();
    }
    int excl = base + lds[t] - v;
    if (i < NN){ row_ptr[i] = excl; cursor[i] = excl; }
    base += lds[1023];
  }
  if (t == 0) row_ptr[NN] = base;
}
__global__ void k_scatter(const int* __restrict__ ei, int* __restrict__ cursor,
                          int* __restrict__ csr_src){
  int e = blockIdx.x * blockDim.x + threadIdx.x;
  if (e >= NETOT) return;
  int s, d;
  if (e < NE){ s = ei[e]; d = ei[NE + e]; } else { s = d = e - NE; }
  int pos = atomicAdd(&cursor[d], 1);
  csr_src[pos] = s;
}

// ---------- fused softmax + input-space aggregation ----------
// agg[n,h,0..K-1] = sum_{e: dst=n} alpha[e,h] * x_bf[src,:]   (block = K/4 threads)
template<int K>
__global__ void k_aggx(const unsigned short* __restrict__ xf, const int* __restrict__ rp,
                       const int* __restrict__ csrc, const float* __restrict__ asrc,
                       const float* __restrict__ adst, unsigned short* __restrict__ agg){
  const int n = blockIdx.x, t = threadIdx.x;
  __shared__ float sm[4], srd[4];
  int beg = rp[n], end = rp[n + 1];
  float4 ad = ((const float4*)adst)[n];
  if (t < 64){
    float m0 = -1e30f, m1 = -1e30f, m2 = -1e30f, m3 = -1e30f;
    for (int i = beg + t; i < end; i += 64){
      int s = csrc[i];
      float4 as = ((const float4*)asrc)[s];
      float v0 = as.x + ad.x; v0 = v0 > 0.f ? v0 : 0.2f * v0; m0 = fmaxf(m0, v0);
      float v1 = as.y + ad.y; v1 = v1 > 0.f ? v1 : 0.2f * v1; m1 = fmaxf(m1, v1);
      float v2 = as.z + ad.z; v2 = v2 > 0.f ? v2 : 0.2f * v2; m2 = fmaxf(m2, v2);
      float v3 = as.w + ad.w; v3 = v3 > 0.f ? v3 : 0.2f * v3; m3 = fmaxf(m3, v3);
    }
#pragma unroll
    for (int off = 32; off; off >>= 1){
      m0 = fmaxf(m0, __shfl_xor(m0, off));
      m1 = fmaxf(m1, __shfl_xor(m1, off));
      m2 = fmaxf(m2, __shfl_xor(m2, off));
      m3 = fmaxf(m3, __shfl_xor(m3, off));
    }
    float s0 = 0.f, s1 = 0.f, s2 = 0.f, s3 = 0.f;
    for (int i = beg + t; i < end; i += 64){
      int s = csrc[i];
      float4 as = ((const float4*)asrc)[s];
      float v0 = as.x + ad.x; v0 = v0 > 0.f ? v0 : 0.2f * v0;
      float v1 = as.y + ad.y; v1 = v1 > 0.f ? v1 : 0.2f * v1;
      float v2 = as.z + ad.z; v2 = v2 > 0.f ? v2 : 0.2f * v2;
      float v3 = as.w + ad.w; v3 = v3 > 0.f ? v3 : 0.2f * v3;
      s0 += __expf(v0 - m0); s1 += __expf(v1 - m1);
      s2 += __expf(v2 - m2); s3 += __expf(v3 - m3);
    }
#pragma unroll
    for (int off = 32; off; off >>= 1){
      s0 += __shfl_xor(s0, off); s1 += __shfl_xor(s1, off);
      s2 += __shfl_xor(s2, off); s3 += __shfl_xor(s3, off);
    }
    if (t == 0){
      sm[0] = m0; sm[1] = m1; sm[2] = m2; sm[3] = m3;
      srd[0] = 1.f / (s0 + 1e-16f); srd[1] = 1.f / (s1 + 1e-16f);
      srd[2] = 1.f / (s2 + 1e-16f); srd[3] = 1.f / (s3 + 1e-16f);
    }
  }
  __syncthreads();
  float m0 = sm[0], m1 = sm[1], m2 = sm[2], m3 = sm[3];
  float r0 = srd[0], r1 = srd[1], r2 = srd[2], r3 = srd[3];
  float acc[4][4] = {};
  for (int i = beg; i < end; ++i){
    int s = csrc[i];
    float4 as = ((const float4*)asrc)[s];
    float v0 = as.x + ad.x; v0 = v0 > 0.f ? v0 : 0.2f * v0; float a0 = __expf(v0 - m0) * r0;
    float v1 = as.y + ad.y; v1 = v1 > 0.f ? v1 : 0.2f * v1; float a1 = __expf(v1 - m1) * r1;
    float v2 = as.z + ad.z; v2 = v2 > 0.f ? v2 : 0.2f * v2; float a2 = __expf(v2 - m2) * r2;
    float v3 = as.w + ad.w; v3 = v3 > 0.f ? v3 : 0.2f * v3; float a3 = __expf(v3 - m3) * r3;
    ushort4 xv = *(const ushort4*)(xf + (size_t)s * K + 4 * t);
    float f0 = bf2f(xv.x), f1 = bf2f(xv.y), f2 = bf2f(xv.z), f3 = bf2f(xv.w);
    acc[0][0] += a0 * f0; acc[0][1] += a0 * f1; acc[0][2] += a0 * f2; acc[0][3] += a0 * f3;
    acc[1][0] += a1 * f0; acc[1][1] += a1 * f1; acc[1][2] += a1 * f2; acc[1][3] += a1 * f3;
    acc[2][0] += a2 * f0; acc[2][1] += a2 * f1; acc[2][2] += a2 * f2; acc[2][3] += a2 * f3;
    acc[3][0] += a3 * f0; acc[3][1] += a3 * f1; acc[3][2] += a3 * f2; acc[3][3] += a3 * f3;
  }
#pragma unroll
  for (int h = 0; h < 4; ++h){
    ushort4 pk;
    pk.x = f2bf(acc[h][0]); pk.y = f2bf(acc[h][1]);
    pk.z = f2bf(acc[h][2]); pk.w = f2bf(acc[h][3]);
    *(ushort4*)(agg + (size_t)n * 4 * K + h * K + 4 * t) = pk;
  }
}

// ---------- WcatT[c][h*K+k] = 0.25 * W[k][h*C+c]  (bf16) ----------
__global__ void k_tcvt_cat(const float* __restrict__ W, unsigned short* __restrict__ T,
                           int K, int C){
  __shared__ float tile[32][33];
  int tx = threadIdx.x, ty = threadIdx.y;
  int h = blockIdx.z;
  int c = blockIdx.x * 32 + tx, k = blockIdx.y * 32 + ty;
  tile[ty][tx] = W[(size_t)k * (4 * C) + h * C + c];
  __syncthreads();
  int c2 = blockIdx.x * 32 + ty, k2 = blockIdx.y * 32 + tx;
  T[(size_t)c2 * (4 * K) + h * K + k2] = f2bf(0.25f * tile[tx][ty]);
}

// ---------- 128x256 bf16 GEMM, BK=32, double-buffer, bias fused, bf16 out ----------
__global__ __launch_bounds__(256, 2)
void gemm_bf16(const unsigned short* __restrict__ A, const unsigned short* __restrict__ BT,
               const float* __restrict__ bias, unsigned short* __restrict__ C,
               int M, int N, int K, int ntile){
  __shared__ unsigned short lds[24576];
  const int t = threadIdx.x;
  const int lane = t & 63;
  const int w = t >> 6;
  const int wr = w >> 1, wc = w & 1;
  const int mt = blockIdx.x / ntile, nt = blockIdx.x % ntile;
  const int m0 = mt << 7, n0 = nt << 8;
  const int NK = K >> 5;

  int offA[4], offB[8];
#pragma unroll
  for (int mi = 0; mi < 4; ++mi){
    int row = wr * 64 + mi * 16 + (lane & 15);
    offA[mi] = row * 32 + (((lane >> 4) ^ ((row >> 1) & 3)) << 3);
  }
#pragma unroll
  for (int ni = 0; ni < 8; ++ni){
    int row = wc * 128 + ni * 16 + (lane & 15);
    offB[ni] = 4096 + row * 32 + (((lane >> 4) ^ ((row >> 1) & 3)) << 3);
  }

  const unsigned short* srcA[2]; int dstA[2];
#pragma unroll
  for (int j = 0; j < 2; ++j){
    int rA = w * 32 + j * 16 + (lane >> 2);
    int gr = m0 + rA; if (gr >= M) gr = M - 1;
    srcA[j] = A + (size_t)gr * K + (((lane & 3) ^ ((rA >> 1) & 3)) << 3);
    dstA[j] = w * 1024 + j * 512 + lane * 8;
  }
  const unsigned short* srcB[4]; int dstB[4];
#pragma unroll
  for (int j = 0; j < 4; ++j){
    int rB = w * 64 + j * 16 + (lane >> 2);
    srcB[j] = BT + (size_t)(n0 + rB) * K + (((lane & 3) ^ ((rB >> 1) & 3)) << 3);
    dstB[j] = 4096 + w * 2048 + j * 512 + lane * 8;
  }

#define STAGE(ks, bo) { int _k = (ks) << 5; \
    gload16(srcA[0] + _k, &lds[(bo) + dstA[0]]); \
    gload16(srcA[1] + _k, &lds[(bo) + dstA[1]]); \
    gload16(srcB[0] + _k, &lds[(bo) + dstB[0]]); \
    gload16(srcB[1] + _k, &lds[(bo) + dstB[1]]); \
    gload16(srcB[2] + _k, &lds[(bo) + dstB[2]]); \
    gload16(srcB[3] + _k, &lds[(bo) + dstB[3]]); }

  f32x4 acc[4][8];
#pragma unroll
  for (int i = 0; i < 4; ++i)
#pragma unroll
    for (int j = 0; j < 8; ++j) acc[i][j] = (f32x4){0.f, 0.f, 0.f, 0.f};

  STAGE(0, 0);
  asm volatile("s_waitcnt vmcnt(0)" ::: "memory");
  __builtin_amdgcn_sched_barrier(0);
  __builtin_amdgcn_s_barrier();
  __builtin_amdgcn_sched_barrier(0);

  for (int ks = 0; ks < NK; ++ks){
    const int bo = (ks & 1) * 12288;
    s16x8 av[4], bv[8];
#pragma unroll
    for (int i = 0; i < 4; ++i) av[i] = *(const s16x8*)&lds[bo + offA[i]];
#pragma unroll
    for (int i = 0; i < 8; ++i) bv[i] = *(const s16x8*)&lds[bo + offB[i]];
    if (ks + 1 < NK) STAGE(ks + 1, 12288 - bo);
    __builtin_amdgcn_s_setprio(1);
#pragma unroll
    for (int mi = 0; mi < 4; ++mi)
#pragma unroll
      for (int ni = 0; ni < 8; ++ni)
        acc[mi][ni] = __builtin_amdgcn_mfma_f32_16x16x32_bf16(av[mi], bv[ni], acc[mi][ni], 0, 0, 0);
    __builtin_amdgcn_s_setprio(0);
    asm volatile("s_waitcnt vmcnt(0)" ::: "memory");
    __builtin_amdgcn_sched_barrier(0);
    __builtin_amdgcn_s_barrier();
    __builtin_amdgcn_sched_barrier(0);
  }
#undef STAGE

  // bias per owned column
  float bb[8];
#pragma unroll
  for (int ni = 0; ni < 8; ++ni)
    bb[ni] = bias[n0 + wc * 128 + ni * 16 + (lane & 15)];

  // epilogue: repack C through LDS, coalesced 16B stores
#pragma unroll
  for (int h = 0; h < 2; ++h){
    if (wr == h){
#pragma unroll
      for (int mi = 0; mi < 4; ++mi)
#pragma unroll
        for (int ni = 0; ni < 8; ++ni)
#pragma unroll
          for (int r = 0; r < 4; ++r){
            int rl = mi * 16 + ((lane >> 4) << 2) + r;
            int col = wc * 128 + ni * 16 + (lane & 15);
            int byte = (rl * 512 + col * 2) ^ (((rl >> 2) & 3) << 5);
            *(unsigned short*)((char*)lds + byte) = f2bf(acc[mi][ni][r] + bb[ni]);
          }
    }
    __syncthreads();
#pragma unroll
    for (int it = 0; it < 8; ++it){
      int idx = it * 256 + t;
      int rl = idx >> 5, c16 = idx & 31;
      int byte = (rl * 512 + c16 * 16) ^ (((rl >> 2) & 3) << 5);
      s16x8 v = *(const s16x8*)((const char*)lds + byte);
      int grow = m0 + h * 64 + rl;
      if (grow < M)
        *(s16x8*)(C + (size_t)grow * N + n0 + c16 * 8) = v;
    }
    __syncthreads();
  }
}

// ---------- pooling (bf16 input) ----------
__global__ void k_pool(const unsigned short* __restrict__ h2, const int* __restrict__ batch,
                       float* __restrict__ sums, int* __restrict__ cnt){
  int n0 = blockIdx.x * 64;
  int t = threadIdx.x;
  int nend = n0 + 64; if (nend > NN) nend = NN;
  int cur = batch[n0];
  float acc = 0.f; int run = 0;
  for (int n = n0; n < nend; ++n){
    int b = batch[n];
    if (b != cur){
      atomicAdd(&sums[cur * 256 + t], acc);
      if (t == 0) atomicAdd(&cnt[cur], run);
      acc = 0.f; run = 0; cur = b;
    }
    acc += bf2f(h2[(size_t)n * 256 + t]);
    run++;
  }
  atomicAdd(&sums[cur * 256 + t], acc);
  if (t == 0) atomicAdd(&cnt[cur], run);
}

__global__ void k_fc(const float* __restrict__ sums, const int* __restrict__ cnt,
                     const float* __restrict__ fcW, const float* __restrict__ fcb,
                     float* __restrict__ out){
  int b = blockIdx.x, t = threadIdx.x;
  int c = cnt[b]; if (c < 1) c = 1;
  float inv = 1.f / (float)c;
  float v = sums[b * 256 + t] * inv;
  float p0 = v * fcW[t * 2];
  float p1 = v * fcW[t * 2 + 1];
#pragma unroll
  for (int off = 32; off; off >>= 1){
    p0 += __shfl_xor(p0, off);
    p1 += __shfl_xor(p1, off);
  }
  __shared__ float r0[4], r1[4];
  if ((t & 63) == 0){ r0[t >> 6] = p0; r1[t >> 6] = p1; }
  __syncthreads();
  if (t == 0){
    out[b * 2 + 0] = r0[0] + r0[1] + r0[2] + r0[3] + fcb[0];
    out[b * 2 + 1] = r1[0] + r1[1] + r1[2] + r1[3] + fcb[1];
  }
}

extern "C" void kernel_launch(void* const* d_in, const int* in_sizes, int n_in,
                              void* d_out, int out_size, void* d_ws, size_t ws_size,
                              hipStream_t stream){
  const float* x      = (const float*)d_in[0];
  const int*   ei     = (const int*)d_in[1];
  const int*   batch  = (const int*)d_in[2];
  const float* W1     = (const float*)d_in[3];
  const float* a_src1 = (const float*)d_in[4];
  const float* a_dst1 = (const float*)d_in[5];
  const float* b1     = (const float*)d_in[6];
  const float* W2     = (const float*)d_in[7];
  const float* a_src2 = (const float*)d_in[8];
  const float* a_dst2 = (const float*)d_in[9];
  const float* b2     = (const float*)d_in[10];
  const float* fcW    = (const float*)d_in[11];
  const float* fcb    = (const float*)d_in[12];
  float* out = (float*)d_out;
  (void)in_sizes; (void)n_in; (void)out_size; (void)ws_size;

  char* ws = (char*)d_ws;
  size_t off = 0;
  auto take = [&](size_t bytes) -> char* {
    char* p = ws + off;
    off += (bytes + 255) & ~(size_t)255;
    return p;
  };
  char* slabA = take(122880000);                       // agg1 [20000,4,768]; later agg2 [20000,4,512]
  unsigned short* agg1 = (unsigned short*)slabA;
  unsigned short* agg2 = (unsigned short*)slabA;
  char* slabB = take(30720000);                        // x_bf [20000,768]; later h2_bf [20000,256]
  unsigned short* x_bf  = (unsigned short*)slabB;
  unsigned short* h2_bf = (unsigned short*)slabB;
  unsigned short* h1_bf = (unsigned short*)take(20480000);  // [20000,512]
  unsigned short* Wc1T  = (unsigned short*)take(3145728);   // [512,3072]
  unsigned short* Wc2T  = (unsigned short*)take(1048576);   // [256,2048]
  float* va     = (float*)take(24576);                 // [8, K<=768]
  float* asrc   = (float*)take(320000);
  float* adst   = (float*)take(320000);
  int* counts   = (int*)take(80004);
  int* row_ptr  = (int*)take(80004);
  int* cursor   = (int*)take(80004);
  int* csr_src  = (int*)take(720000);
  float* sums   = (float*)take(131072);
  int* cnt      = (int*)take(512);

  const int egrid = (NETOT + 255) / 256;

  // ---- CSR (shared by both layers) ----
  hipMemsetAsync(counts, 0, NN * 4, stream);
  k_count<<<egrid, 256, 0, stream>>>(ei, counts);
  k_scan<<<1, 1024, 0, stream>>>(counts, row_ptr, cursor);
  k_scatter<<<egrid, 256, 0, stream>>>(ei, cursor, csr_src);

  // ---- layer 1 (K=768, C=512) ----
  k_cvt<<<(3840000 + 255) / 256, 256, 0, stream>>>(x, x_bf, 3840000);
  k_va<<<192, 256, 0, stream>>>(W1, a_src1, a_dst1, va, 768, 512);
  k_alpha_in<768><<<NN / 4, 256, 0, stream>>>(x_bf, va, asrc, adst);
  k_tcvt_cat<<<dim3(16, 24, 4), dim3(32, 32), 0, stream>>>(W1, Wc1T, 768, 512);
  k_aggx<768><<<NN, 192, 0, stream>>>(x_bf, row_ptr, csr_src, asrc, adst, agg1);
  gemm_bf16<<<157 * 2, 256, 0, stream>>>(agg1, Wc1T, b1, h1_bf, NN, 512, 3072, 2);

  // ---- layer 2 (K=512, C=256) ----
  k_va<<<128, 256, 0, stream>>>(W2, a_src2, a_dst2, va, 512, 256);
  k_alpha_in<512><<<NN / 4, 256, 0, stream>>>(h1_bf, va, asrc, adst);
  k_tcvt_cat<<<dim3(8, 16, 4), dim3(32, 32), 0, stream>>>(W2, Wc2T, 512, 256);
  k_aggx<512><<<NN, 128, 0, stream>>>(h1_bf, row_ptr, csr_src, asrc, adst, agg2);
  gemm_bf16<<<157 * 1, 256, 0, stream>>>(agg2, Wc2T, b2, h2_bf, NN, 256, 2048, 1);

  // ---- pool + fc ----
  hipMemsetAsync(sums, 0, 131072, stream);
  hipMemsetAsync(cnt, 0, 512, stream);
  k_pool<<<(NN + 63) / 64, 256, 0, stream>>>(h2_bf, batch, sums, cnt);
  k_fc<<<NB, 256, 0, stream>>>(sums, cnt, fcW, fcb, out);
}

// Round 6
// 510.380 us; speedup vs baseline: 1.9437x; 1.0149x over previous
//
#include <hip/hip_runtime.h>

#define NN    20000
#define NE    160000
#define NETOT 180000
#define NB    128

typedef __attribute__((ext_vector_type(4))) float f32x4;
typedef __attribute__((ext_vector_type(8))) short s16x8;

__device__ __forceinline__ unsigned short f2bf(float f){
  unsigned u = __float_as_uint(f);
  return (unsigned short)((u + 0x7FFFu + ((u >> 16) & 1u)) >> 16);
}
__device__ __forceinline__ float bf2f(unsigned short h){
  return __uint_as_float(((unsigned)h) << 16);
}
__device__ __forceinline__ void gload16(const void* g, void* l){
  __builtin_amdgcn_global_load_lds((const __attribute__((address_space(1))) void*)g,
                                   (__attribute__((address_space(3))) void*)l, 16, 0, 0);
}

// ---------- f32 -> bf16 convert ----------
__global__ void k_cvt(const float* __restrict__ in, unsigned short* __restrict__ outp, int n4){
  int i = blockIdx.x * blockDim.x + threadIdx.x;
  if (i >= n4) return;
  float4 v = ((const float4*)in)[i];
  ushort4 h;
  h.x = f2bf(v.x); h.y = f2bf(v.y); h.z = f2bf(v.z); h.w = f2bf(v.w);
  ((ushort4*)outp)[i] = h;
}

// ---------- va[a][k] = sum_c W[k][h*C+c] * a_{src,dst}[h][c] ----------
__global__ void k_va(const float* __restrict__ W, const float* __restrict__ aS,
                     const float* __restrict__ aD, float* __restrict__ va, int K, int C){
  __shared__ float a_s[2048], a_d[2048];
  int t = threadIdx.x;
  int HC = 4 * C;
  for (int i = t; i < HC; i += 256){ a_s[i] = aS[i]; a_d[i] = aD[i]; }
  __syncthreads();
  int k = blockIdx.x * 4 + (t >> 6);
  int lane = t & 63;
  if (k >= K) return;
  float ss[4] = {0.f,0.f,0.f,0.f}, dd[4] = {0.f,0.f,0.f,0.f};
  for (int h = 0; h < 4; ++h)
    for (int c0 = 0; c0 < C; c0 += 64){
      float wv = W[(size_t)k * HC + h * C + c0 + lane];
      ss[h] += wv * a_s[h * C + c0 + lane];
      dd[h] += wv * a_d[h * C + c0 + lane];
    }
#pragma unroll
  for (int off = 32; off; off >>= 1)
#pragma unroll
    for (int h = 0; h < 4; ++h){
      ss[h] += __shfl_xor(ss[h], off);
      dd[h] += __shfl_xor(dd[h], off);
    }
  if (lane == 0)
#pragma unroll
    for (int h = 0; h < 4; ++h){
      va[h * K + k] = ss[h];
      va[(4 + h) * K + k] = dd[h];
    }
}

// ---------- alpha_src/dst[n,h] = sum_k x_bf[n,k] * va[a][k] ----------
template<int K>                          // 256 thr = 4 waves, node per wave
__global__ void k_alpha_in(const unsigned short* __restrict__ xf, const float* __restrict__ va,
                           float* __restrict__ asrc, float* __restrict__ adst){
  __shared__ float v_s[8 * K];
  int t = threadIdx.x;
  for (int i = t; i < 8 * K; i += 256) v_s[i] = va[i];
  __syncthreads();
  int n = blockIdx.x * 4 + (t >> 6);
  if (n >= NN) return;
  int lane = t & 63;
  const unsigned short* xr = xf + (size_t)n * K;
  float s[8] = {};
#pragma unroll
  for (int j = 0; j < K / 256; ++j){
    int idx = j * 256 + lane * 4;
    ushort4 xv = *(const ushort4*)(xr + idx);
    float f0 = bf2f(xv.x), f1 = bf2f(xv.y), f2 = bf2f(xv.z), f3 = bf2f(xv.w);
#pragma unroll
    for (int a = 0; a < 8; ++a){
      const float* vp = v_s + a * K + idx;
      s[a] += f0 * vp[0] + f1 * vp[1] + f2 * vp[2] + f3 * vp[3];
    }
  }
#pragma unroll
  for (int off = 32; off; off >>= 1)
#pragma unroll
    for (int a = 0; a < 8; ++a) s[a] += __shfl_xor(s[a], off);
  if (lane == 0){
    ((float4*)asrc)[n] = make_float4(s[0], s[1], s[2], s[3]);
    ((float4*)adst)[n] = make_float4(s[4], s[5], s[6], s[7]);
  }
}

// ---------- CSR build ----------
__global__ void k_count(const int* __restrict__ ei, int* __restrict__ counts){
  int e = blockIdx.x * blockDim.x + threadIdx.x;
  if (e >= NETOT) return;
  int d = (e < NE) ? ei[NE + e] : (e - NE);
  atomicAdd(&counts[d], 1);
}
// wave-shuffle scan; also zeroes sums/cnt for the pool stage
__global__ void k_scan(const int* __restrict__ counts, int* __restrict__ row_ptr,
                       int* __restrict__ cursor, float* __restrict__ sums,
                       int* __restrict__ cnt){
  int t = threadIdx.x;                     // 1024
  for (int i = t; i < NB * 256; i += 1024) sums[i] = 0.f;
  if (t < NB) cnt[t] = 0;
  __shared__ int wsum[16];
  int wid = t >> 6, lane = t & 63;
  int base = 0;
  for (int c0 = 0; c0 < NN; c0 += 1024){
    int i = c0 + t;
    int v = (i < NN) ? counts[i] : 0;
    int s = v;
#pragma unroll
    for (int off = 1; off < 64; off <<= 1){
      int u = __shfl_up(s, off);
      if (lane >= off) s += u;
    }
    if (lane == 63) wsum[wid] = s;
    __syncthreads();
    if (wid == 0){
      int ws = (lane < 16) ? wsum[lane] : 0;
#pragma unroll
      for (int off = 1; off < 16; off <<= 1){
        int u = __shfl_up(ws, off);
        if (lane >= off) ws += u;
      }
      if (lane < 16) wsum[lane] = ws;
    }
    __syncthreads();
    int excl = base + (wid ? wsum[wid - 1] : 0) + s - v;
    if (i < NN){ row_ptr[i] = excl; cursor[i] = excl; }
    base += wsum[15];
    __syncthreads();
  }
  if (t == 0) row_ptr[NN] = base;
}
__global__ void k_scatter(const int* __restrict__ ei, int* __restrict__ cursor,
                          int* __restrict__ csr_src){
  int e = blockIdx.x * blockDim.x + threadIdx.x;
  if (e >= NETOT) return;
  int s, d;
  if (e < NE){ s = ei[e]; d = ei[NE + e]; } else { s = d = e - NE; }
  int pos = atomicAdd(&cursor[d], 1);
  csr_src[pos] = s;
}

// ---------- segment softmax: one wave per node, writes NORMALIZED alpha ----------
__global__ void k_edge(const int* __restrict__ rp, const int* __restrict__ csrc,
                       const float* __restrict__ asrc, const float* __restrict__ adst,
                       float* __restrict__ alpha4){
  int n = blockIdx.x * 4 + (threadIdx.x >> 6);
  if (n >= NN) return;
  int lane = threadIdx.x & 63;
  int beg = rp[n], end = rp[n + 1];
  float4 ad = ((const float4*)adst)[n];
  float mx0 = -1e30f, mx1 = -1e30f, mx2 = -1e30f, mx3 = -1e30f;
  for (int i = beg + lane; i < end; i += 64){
    int s = csrc[i];
    float4 as = ((const float4*)asrc)[s];
    float v0 = as.x + ad.x; v0 = v0 > 0.f ? v0 : 0.2f * v0; mx0 = fmaxf(mx0, v0);
    float v1 = as.y + ad.y; v1 = v1 > 0.f ? v1 : 0.2f * v1; mx1 = fmaxf(mx1, v1);
    float v2 = as.z + ad.z; v2 = v2 > 0.f ? v2 : 0.2f * v2; mx2 = fmaxf(mx2, v2);
    float v3 = as.w + ad.w; v3 = v3 > 0.f ? v3 : 0.2f * v3; mx3 = fmaxf(mx3, v3);
  }
#pragma unroll
  for (int off = 32; off; off >>= 1){
    mx0 = fmaxf(mx0, __shfl_xor(mx0, off));
    mx1 = fmaxf(mx1, __shfl_xor(mx1, off));
    mx2 = fmaxf(mx2, __shfl_xor(mx2, off));
    mx3 = fmaxf(mx3, __shfl_xor(mx3, off));
  }
  float s0 = 0.f, s1 = 0.f, s2 = 0.f, s3 = 0.f;
  for (int i = beg + lane; i < end; i += 64){
    int s = csrc[i];
    float4 as = ((const float4*)asrc)[s];
    float v0 = as.x + ad.x; v0 = v0 > 0.f ? v0 : 0.2f * v0;
    float v1 = as.y + ad.y; v1 = v1 > 0.f ? v1 : 0.2f * v1;
    float v2 = as.z + ad.z; v2 = v2 > 0.f ? v2 : 0.2f * v2;
    float v3 = as.w + ad.w; v3 = v3 > 0.f ? v3 : 0.2f * v3;
    float e0 = __expf(v0 - mx0), e1 = __expf(v1 - mx1);
    float e2 = __expf(v2 - mx2), e3 = __expf(v3 - mx3);
    s0 += e0; s1 += e1; s2 += e2; s3 += e3;
    ((float4*)alpha4)[i] = make_float4(e0, e1, e2, e3);
  }
#pragma unroll
  for (int off = 32; off; off >>= 1){
    s0 += __shfl_xor(s0, off); s1 += __shfl_xor(s1, off);
    s2 += __shfl_xor(s2, off); s3 += __shfl_xor(s3, off);
  }
  float r0 = 1.f / (s0 + 1e-16f), r1 = 1.f / (s1 + 1e-16f);
  float r2 = 1.f / (s2 + 1e-16f), r3 = 1.f / (s3 + 1e-16f);
  for (int i = beg + lane; i < end; i += 64){
    float4 v = ((const float4*)alpha4)[i];
    ((float4*)alpha4)[i] = make_float4(v.x * r0, v.y * r1, v.z * r2, v.w * r3);
  }
}

// ---------- input-space aggregation: pure gather-fma ----------
// agg[n,h,:] = sum_{e: dst=n} alpha[e,h] * x_bf[src,:]   (block = K/4 threads)
template<int K>
__global__ void k_aggx(const unsigned short* __restrict__ xf, const int* __restrict__ rp,
                       const int* __restrict__ csrc, const float* __restrict__ alpha4,
                       unsigned short* __restrict__ agg){
  const int n = blockIdx.x, t = threadIdx.x;
  int beg = rp[n], end = rp[n + 1];
  float acc[4][4] = {};
  for (int i = beg; i < end; ++i){
    int s = csrc[i];
    float4 al = ((const float4*)alpha4)[i];
    ushort4 xv = *(const ushort4*)(xf + (size_t)s * K + 4 * t);
    float f0 = bf2f(xv.x), f1 = bf2f(xv.y), f2 = bf2f(xv.z), f3 = bf2f(xv.w);
    acc[0][0] += al.x * f0; acc[0][1] += al.x * f1; acc[0][2] += al.x * f2; acc[0][3] += al.x * f3;
    acc[1][0] += al.y * f0; acc[1][1] += al.y * f1; acc[1][2] += al.y * f2; acc[1][3] += al.y * f3;
    acc[2][0] += al.z * f0; acc[2][1] += al.z * f1; acc[2][2] += al.z * f2; acc[2][3] += al.z * f3;
    acc[3][0] += al.w * f0; acc[3][1] += al.w * f1; acc[3][2] += al.w * f2; acc[3][3] += al.w * f3;
  }
#pragma unroll
  for (int h = 0; h < 4; ++h){
    ushort4 pk;
    pk.x = f2bf(acc[h][0]); pk.y = f2bf(acc[h][1]);
    pk.z = f2bf(acc[h][2]); pk.w = f2bf(acc[h][3]);
    *(ushort4*)(agg + (size_t)n * 4 * K + h * K + 4 * t) = pk;
  }
}

// ---------- WcatT[c][h*K+k] = 0.25 * W[k][h*C+c]  (bf16) ----------
__global__ void k_tcvt_cat(const float* __restrict__ W, unsigned short* __restrict__ T,
                           int K, int C){
  __shared__ float tile[32][33];
  int tx = threadIdx.x, ty = threadIdx.y;
  int h = blockIdx.z;
  int c = blockIdx.x * 32 + tx, k = blockIdx.y * 32 + ty;
  tile[ty][tx] = W[(size_t)k * (4 * C) + h * C + c];
  __syncthreads();
  int c2 = blockIdx.x * 32 + ty, k2 = blockIdx.y * 32 + tx;
  T[(size_t)c2 * (4 * K) + h * K + k2] = f2bf(0.25f * tile[tx][ty]);
}

// ---------- 128x256 bf16 GEMM, BK=32, 3-stage ring + counted vmcnt ----------
__global__ __launch_bounds__(256, 2)
void gemm_bf16(const unsigned short* __restrict__ A, const unsigned short* __restrict__ BT,
               const float* __restrict__ bias, unsigned short* __restrict__ C,
               int M, int N, int K, int ntile){
  __shared__ unsigned short lds[36864];       // 3 stages x (A 4096 + B 8192) = 72 KB
  const int t = threadIdx.x;
  const int lane = t & 63;
  const int w = t >> 6;
  const int wr = w >> 1, wc = w & 1;
  const int mt = blockIdx.x / ntile, nt = blockIdx.x % ntile;
  const int m0 = mt << 7, n0 = nt << 8;
  const int NK = K >> 5;

  int offA[4], offB[8];
#pragma unroll
  for (int mi = 0; mi < 4; ++mi){
    int row = wr * 64 + mi * 16 + (lane & 15);
    offA[mi] = row * 32 + (((lane >> 4) ^ ((row >> 1) & 3)) << 3);
  }
#pragma unroll
  for (int ni = 0; ni < 8; ++ni){
    int row = wc * 128 + ni * 16 + (lane & 15);
    offB[ni] = 4096 + row * 32 + (((lane >> 4) ^ ((row >> 1) & 3)) << 3);
  }

  const unsigned short* srcA[2]; int dstA[2];
#pragma unroll
  for (int j = 0; j < 2; ++j){
    int rA = w * 32 + j * 16 + (lane >> 2);
    int gr = m0 + rA; if (gr >= M) gr = M - 1;
    srcA[j] = A + (size_t)gr * K + (((lane & 3) ^ ((rA >> 1) & 3)) << 3);
    dstA[j] = w * 1024 + j * 512 + lane * 8;
  }
  const unsigned short* srcB[4]; int dstB[4];
#pragma unroll
  for (int j = 0; j < 4; ++j){
    int rB = w * 64 + j * 16 + (lane >> 2);
    srcB[j] = BT + (size_t)(n0 + rB) * K + (((lane & 3) ^ ((rB >> 1) & 3)) << 3);
    dstB[j] = 4096 + w * 2048 + j * 512 + lane * 8;
  }

#define STAGE(ks, bo_) { int _k = (ks) << 5; \
    gload16(srcA[0] + _k, &lds[(bo_) + dstA[0]]); \
    gload16(srcA[1] + _k, &lds[(bo_) + dstA[1]]); \
    gload16(srcB[0] + _k, &lds[(bo_) + dstB[0]]); \
    gload16(srcB[1] + _k, &lds[(bo_) + dstB[1]]); \
    gload16(srcB[2] + _k, &lds[(bo_) + dstB[2]]); \
    gload16(srcB[3] + _k, &lds[(bo_) + dstB[3]]); }

  f32x4 acc[4][8];
#pragma unroll
  for (int i = 0; i < 4; ++i)
#pragma unroll
    for (int j = 0; j < 8; ++j) acc[i][j] = (f32x4){0.f, 0.f, 0.f, 0.f};

  // prologue: fill the 3-deep ring (18 loads in flight)
  STAGE(0, 0); STAGE(1, 12288); STAGE(2, 24576);

  int bo = 0;
  for (int ks = 0; ks < NK; ++ks){
    // retire stage ks (leave up to 12 newer loads in flight)
    if (ks < NK - 2)      { asm volatile("s_waitcnt vmcnt(12)" ::: "memory"); }
    else if (ks == NK - 2){ asm volatile("s_waitcnt vmcnt(6)" ::: "memory"); }
    else                  { asm volatile("s_waitcnt vmcnt(0)" ::: "memory"); }
    __builtin_amdgcn_sched_barrier(0);
    __builtin_amdgcn_s_barrier();           // stage ks visible to all waves
    __builtin_amdgcn_sched_barrier(0);

    s16x8 av[4], bv[8];
#pragma unroll
    for (int i = 0; i < 4; ++i) av[i] = *(const s16x8*)&lds[bo + offA[i]];
#pragma unroll
    for (int i = 0; i < 8; ++i) bv[i] = *(const s16x8*)&lds[bo + offB[i]];
    asm volatile("s_waitcnt lgkmcnt(0)" ::: "memory");
    __builtin_amdgcn_sched_barrier(0);
    __builtin_amdgcn_s_barrier();           // all waves done reading buf[ks]
    __builtin_amdgcn_sched_barrier(0);
    if (ks + 3 < NK) STAGE(ks + 3, bo);     // safe to overwrite ring slot

    __builtin_amdgcn_s_setprio(1);
#pragma unroll
    for (int mi = 0; mi < 4; ++mi)
#pragma unroll
      for (int ni = 0; ni < 8; ++ni)
        acc[mi][ni] = __builtin_amdgcn_mfma_f32_16x16x32_bf16(av[mi], bv[ni], acc[mi][ni], 0, 0, 0);
    __builtin_amdgcn_s_setprio(0);
    bo += 12288; if (bo == 36864) bo = 0;
  }
#undef STAGE

  float bb[8];
#pragma unroll
  for (int ni = 0; ni < 8; ++ni)
    bb[ni] = bias[n0 + wc * 128 + ni * 16 + (lane & 15)];

  // epilogue: repack C through LDS, coalesced 16B stores
  __builtin_amdgcn_s_barrier();
#pragma unroll
  for (int h = 0; h < 2; ++h){
    if (wr == h){
#pragma unroll
      for (int mi = 0; mi < 4; ++mi)
#pragma unroll
        for (int ni = 0; ni < 8; ++ni)
#pragma unroll
          for (int r = 0; r < 4; ++r){
            int rl = mi * 16 + ((lane >> 4) << 2) + r;
            int col = wc * 128 + ni * 16 + (lane & 15);
            int byte = (rl * 512 + col * 2) ^ (((rl >> 2) & 3) << 5);
            *(unsigned short*)((char*)lds + byte) = f2bf(acc[mi][ni][r] + bb[ni]);
          }
    }
    __syncthreads();
#pragma unroll
    for (int it = 0; it < 8; ++it){
      int idx = it * 256 + t;
      int rl = idx >> 5, c16 = idx & 31;
      int byte = (rl * 512 + c16 * 16) ^ (((rl >> 2) & 3) << 5);
      s16x8 v = *(const s16x8*)((const char*)lds + byte);
      int grow = m0 + h * 64 + rl;
      if (grow < M)
        *(s16x8*)(C + (size_t)grow * N + n0 + c16 * 8) = v;
    }
    __syncthreads();
  }
}

// ---------- pooling (bf16 input) ----------
__global__ void k_pool(const unsigned short* __restrict__ h2, const int* __restrict__ batch,
                       float* __restrict__ sums, int* __restrict__ cnt){
  int n0 = blockIdx.x * 64;
  int t = threadIdx.x;
  int nend = n0 + 64; if (nend > NN) nend = NN;
  int cur = batch[n0];
  float acc = 0.f; int run = 0;
  for (int n = n0; n < nend; ++n){
    int b = batch[n];
    if (b != cur){
      atomicAdd(&sums[cur * 256 + t], acc);
      if (t == 0) atomicAdd(&cnt[cur], run);
      acc = 0.f; run = 0; cur = b;
    }
    acc += bf2f(h2[(size_t)n * 256 + t]);
    run++;
  }
  atomicAdd(&sums[cur * 256 + t], acc);
  if (t == 0) atomicAdd(&cnt[cur], run);
}

__global__ void k_fc(const float* __restrict__ sums, const int* __restrict__ cnt,
                     const float* __restrict__ fcW, const float* __restrict__ fcb,
                     float* __restrict__ out){
  int b = blockIdx.x, t = threadIdx.x;
  int c = cnt[b]; if (c < 1) c = 1;
  float inv = 1.f / (float)c;
  float v = sums[b * 256 + t] * inv;
  float p0 = v * fcW[t * 2];
  float p1 = v * fcW[t * 2 + 1];
#pragma unroll
  for (int off = 32; off; off >>= 1){
    p0 += __shfl_xor(p0, off);
    p1 += __shfl_xor(p1, off);
  }
  __shared__ float r0[4], r1[4];
  if ((t & 63) == 0){ r0[t >> 6] = p0; r1[t >> 6] = p1; }
  __syncthreads();
  if (t == 0){
    out[b * 2 + 0] = r0[0] + r0[1] + r0[2] + r0[3] + fcb[0];
    out[b * 2 + 1] = r1[0] + r1[1] + r1[2] + r1[3] + fcb[1];
  }
}

extern "C" void kernel_launch(void* const* d_in, const int* in_sizes, int n_in,
                              void* d_out, int out_size, void* d_ws, size_t ws_size,
                              hipStream_t stream){
  const float* x      = (const float*)d_in[0];
  const int*   ei     = (const int*)d_in[1];
  const int*   batch  = (const int*)d_in[2];
  const float* W1     = (const float*)d_in[3];
  const float* a_src1 = (const float*)d_in[4];
  const float* a_dst1 = (const float*)d_in[5];
  const float* b1     = (const float*)d_in[6];
  const float* W2     = (const float*)d_in[7];
  const float* a_src2 = (const float*)d_in[8];
  const float* a_dst2 = (const float*)d_in[9];
  const float* b2     = (const float*)d_in[10];
  const float* fcW    = (const float*)d_in[11];
  const float* fcb    = (const float*)d_in[12];
  float* out = (float*)d_out;
  (void)in_sizes; (void)n_in; (void)out_size; (void)ws_size;

  char* ws = (char*)d_ws;
  size_t off = 0;
  auto take = [&](size_t bytes) -> char* {
    char* p = ws + off;
    off += (bytes + 255) & ~(size_t)255;
    return p;
  };
  char* slabA = take(122880000);                       // agg1 [20000,4,768]; later agg2 [20000,4,512]
  unsigned short* agg1 = (unsigned short*)slabA;
  unsigned short* agg2 = (unsigned short*)slabA;
  char* slabB = take(30720000);                        // x_bf [20000,768]; later h2_bf [20000,256]
  unsigned short* x_bf  = (unsigned short*)slabB;
  unsigned short* h2_bf = (unsigned short*)slabB;
  unsigned short* h1_bf = (unsigned short*)take(20480000);  // [20000,512]
  unsigned short* Wc1T  = (unsigned short*)take(3145728);   // [512,3072]
  unsigned short* Wc2T  = (unsigned short*)take(1048576);   // [256,2048]
  float* va     = (float*)take(24576);
  float* asrc   = (float*)take(320000);
  float* adst   = (float*)take(320000);
  float* alpha4 = (float*)take((size_t)NETOT * 16);
  int* counts   = (int*)take(80004);
  int* row_ptr  = (int*)take(80004);
  int* cursor   = (int*)take(80004);
  int* csr_src  = (int*)take(720000);
  float* sums   = (float*)take(131072);
  int* cnt      = (int*)take(512);

  const int egrid = (NETOT + 255) / 256;

  // ---- CSR (shared by both layers) ----
  hipMemsetAsync(counts, 0, NN * 4, stream);
  k_count<<<egrid, 256, 0, stream>>>(ei, counts);
  k_scan<<<1, 1024, 0, stream>>>(counts, row_ptr, cursor, sums, cnt);
  k_scatter<<<egrid, 256, 0, stream>>>(ei, cursor, csr_src);

  // ---- layer 1 (K=768, C=512) ----
  k_cvt<<<(3840000 + 255) / 256, 256, 0, stream>>>(x, x_bf, 3840000);
  k_va<<<192, 256, 0, stream>>>(W1, a_src1, a_dst1, va, 768, 512);
  k_alpha_in<768><<<NN / 4, 256, 0, stream>>>(x_bf, va, asrc, adst);
  k_tcvt_cat<<<dim3(16, 24, 4), dim3(32, 32), 0, stream>>>(W1, Wc1T, 768, 512);
  k_edge<<<(NN + 3) / 4, 256, 0, stream>>>(row_ptr, csr_src, asrc, adst, alpha4);
  k_aggx<768><<<NN, 192, 0, stream>>>(x_bf, row_ptr, csr_src, alpha4, agg1);
  gemm_bf16<<<157 * 2, 256, 0, stream>>>(agg1, Wc1T, b1, h1_bf, NN, 512, 3072, 2);

  // ---- layer 2 (K=512, C=256) ----
  k_va<<<128, 256, 0, stream>>>(W2, a_src2, a_dst2, va, 512, 256);
  k_alpha_in<512><<<NN / 4, 256, 0, stream>>>(h1_bf, va, asrc, adst);
  k_tcvt_cat<<<dim3(8, 16, 4), dim3(32, 32), 0, stream>>>(W2, Wc2T, 512, 256);
  k_edge<<<(NN + 3) / 4, 256, 0, stream>>>(row_ptr, csr_src, asrc, adst, alpha4);
  k_aggx<512><<<NN, 128, 0, stream>>>(h1_bf, row_ptr, csr_src, alpha4, agg2);
  gemm_bf16<<<157, 256, 0, stream>>>(agg2, Wc2T, b2, h2_bf, NN, 256, 2048, 1);

  // ---- pool + fc ----
  k_pool<<<(NN + 63) / 64, 256, 0, stream>>>(h2_bf, batch, sums, cnt);
  k_fc<<<NB, 256, 0, stream>>>(sums, cnt, fcW, fcb, out);
}